// Round 3
// baseline (1157.707 us; speedup 1.0000x reference)
//
#include <hip/hip_runtime.h>

#define NN 50000      // nodes
#define NE 800000     // edges
#define NF 128        // node features
#define EF 64         // edge features
#define LSZ 256       // layer size
#define D1 193        // NF+EF+1
#define D2 385        // NF+LSZ+1
#define Y2S 416       // Y2 row stride = 13*32 (gemm3 K, padded)
#define ALD 208       // gemm1 LDS A row stride (bf16 elems)
#define TLD 264       // gemm1 LDS transpose row stride (bf16, 528B: 2-way only)
#define BN_EPS 1e-5f

typedef float f32x4 __attribute__((ext_vector_type(4)));
typedef short s16x8 __attribute__((ext_vector_type(8)));

__device__ __forceinline__ unsigned short f2bf(float f) {
    unsigned u = __float_as_uint(f);
    u += 0x7FFFu + ((u >> 16) & 1u);   // RNE
    return (unsigned short)(u >> 16);
}
__device__ __forceinline__ float bf2f(unsigned short s) {
    return __uint_as_float(((unsigned)s) << 16);
}

// ===========================================================================
// Generic weight pre-pack into MFMA B-fragment order.
// Fragment (s, i): k' = s*32 + (lane>>4)*8 + j ; col n = 16*i + (lane&15).
// Source row = k' (or k'+1 if k' >= batch_row, skipping the rank-1 batch row).
// ===========================================================================
__global__ void prep_w_kernel(const float* __restrict__ W, int ldw, int ncols,
                              int kmax_src, int batch_row, int nfrag, int ksteps,
                              unsigned short* __restrict__ Wp)
{
    int t = blockIdx.x * 256 + threadIdx.x;
    if (t >= ksteps * nfrag * 64) return;
    int lane = t & 63, si = t >> 6;
    int i = si % nfrag, s = si / nfrag;
    int q = lane >> 4, n = (i << 4) + (lane & 15);
    unsigned short v[8];
#pragma unroll
    for (int j = 0; j < 8; j++) {
        int k = s * 32 + q * 8 + j;
        int sr = (batch_row >= 0 && k >= batch_row) ? k + 1 : k;
        v[j] = (sr < kmax_src && n < ncols) ? f2bf(W[(size_t)sr * ldw + n])
                                            : (unsigned short)0;
    }
    *(uint4*)&Wp[(size_t)t * 8] = *(const uint4*)v;
}

// ===========================================================================
// GEMM1: block = 64 edges x 256 cols, 4 waves; wave owns 64 cols (4 N-frags).
// K = 192; batch column applied rank-1 in epilogue.
// A staged through LDS with coalesced row bursts (bf16), B double-buffered.
// MODE 0: BN stats only (bucketed col sum/sumsq)            [fallback]
// MODE 1: CSR order, affine+ReLU, scatter-atomic into aggsum [fallback]
// MODE 2: SOURCE-sorted order (colE arg = eS: edge per source slot;
//         eidx arg = pS: dest-CSR slot per source slot).  A 64-edge block
//         touches only ~4-8 distinct x rows -> x gather is L1/L2-hot.
//         BN stats in regs + Y1 written via LDS transpose as 512B row bursts.
// ===========================================================================
template <int MODE>
__global__ __launch_bounds__(256, 5) void gemm1_mfma(
    const float* __restrict__ x, const int* __restrict__ rowi,
    const int* __restrict__ colE, const int* __restrict__ batch,
    const float* __restrict__ ea, const float* __restrict__ W1,
    const unsigned short* __restrict__ W1p, const int* __restrict__ eidx,
    const float* __restrict__ a1, const float* __restrict__ b1n,
    float* __restrict__ colsum_b, float* __restrict__ colsq_b,
    float* __restrict__ aggsum, unsigned short* __restrict__ y1c)
{
    __shared__ unsigned short Asm[64 * ALD];   // 26.6 KB; reused as transpose buf
    __shared__ int   rowS[64];
    __shared__ int   eSs[64];
    __shared__ float bvalS[64];
    __shared__ int   destS[64];

    const int tid = threadIdx.x;
    const int lane = tid & 63, wave = tid >> 6;
    const int quad = lane >> 4, l15 = lane & 15;
    const int e0 = blockIdx.x * 64;

    if (tid < 64) {
        int sp = e0 + tid;
        int e;
        if (MODE == 1)      { e = eidx[sp]; destS[tid] = colE[e]; }
        else if (MODE == 2) { e = colE[sp]; destS[tid] = eidx[sp]; } // eS / pS
        else                  e = sp;
        eSs[tid] = e;
        int r = rowi[e];
        rowS[tid] = r;
        bvalS[tid] = (float)batch[r];
    }
    __syncthreads();

    // ---- stage A into LDS: x = 2048 float4 (cols 0..127), ea = 1024 float4
    // (cols 128..191). Consecutive lanes -> consecutive cols of the same row.
    // In MODE 2 the x rows repeat within the block (source-sorted) -> L1-hot.
#pragma unroll
    for (int i = 0; i < 12; i++) {
        int idx = i * 256 + tid;
        int row, col4;
        const float* src;
        if (idx < 2048) {                       // compile-time resolvable per i
            row = idx >> 5; col4 = idx & 31;
            src = x + (size_t)rowS[row] * NF + col4 * 4;
        } else {
            int j = idx - 2048;
            row = j >> 4; col4 = 32 + (j & 15);
            src = ea + (size_t)eSs[row] * EF + (col4 - 32) * 4;
        }
        float4 v = *(const float4*)src;
        ushort4 h;
        h.x = f2bf(v.x); h.y = f2bf(v.y); h.z = f2bf(v.z); h.w = f2bf(v.w);
        *(uint2*)&Asm[row * ALD + col4 * 4] = *(uint2*)&h;
    }
    __syncthreads();

    const s16x8* Bp = (const s16x8*)W1p;
    f32x4 acc[4][4];
#pragma unroll
    for (int mf = 0; mf < 4; mf++)
#pragma unroll
        for (int f = 0; f < 4; f++) acc[mf][f] = (f32x4){0.f, 0.f, 0.f, 0.f};

    s16x8 bcur[4], bnxt[4];
#pragma unroll
    for (int f = 0; f < 4; f++)
        bcur[f] = Bp[(size_t)(wave * 4 + f) * 64 + lane];

#pragma unroll
    for (int s = 0; s < 6; s++) {
        if (s < 5) {
#pragma unroll
            for (int f = 0; f < 4; f++)
                bnxt[f] = Bp[(size_t)((s + 1) * 16 + wave * 4 + f) * 64 + lane];
        }
        s16x8 af[4];
#pragma unroll
        for (int mf = 0; mf < 4; mf++)
            af[mf] = *(const s16x8*)&Asm[(mf * 16 + l15) * ALD + s * 32 + quad * 8];
#pragma unroll
        for (int mf = 0; mf < 4; mf++)
#pragma unroll
            for (int f = 0; f < 4; f++)
                acc[mf][f] = __builtin_amdgcn_mfma_f32_16x16x32_bf16(
                    af[mf], bcur[f], acc[mf][f], 0, 0, 0);
#pragma unroll
        for (int f = 0; f < 4; f++) bcur[f] = bnxt[f];
    }

    // C/D: element r of lane = C[row = mf*16 + quad*4 + r][col = 16*i + l15]
    float bv[4][4];
#pragma unroll
    for (int mf = 0; mf < 4; mf++)
#pragma unroll
        for (int r = 0; r < 4; r++) bv[mf][r] = bvalS[mf * 16 + quad * 4 + r];

    if (MODE == 0) {
        const int bucket = blockIdx.x & 63;
#pragma unroll
        for (int f = 0; f < 4; f++) {
            const int col = ((wave * 4 + f) << 4) + l15;
            const float w1b = W1[(size_t)128 * LSZ + col];   // rank-1 batch row
            float s = 0.f, q = 0.f;
#pragma unroll
            for (int mf = 0; mf < 4; mf++)
#pragma unroll
                for (int r = 0; r < 4; r++) {
                    float y = fmaf(bv[mf][r], w1b, acc[mf][f][r]);
                    s += y; q += y * y;
                }
            s += __shfl_xor(s, 16); s += __shfl_xor(s, 32);
            q += __shfl_xor(q, 16); q += __shfl_xor(q, 32);
            if (quad == 0) {
                atomicAdd(&colsum_b[bucket * LSZ + col], s);
                atomicAdd(&colsq_b [bucket * LSZ + col], q);
            }
        }
    } else if (MODE == 2) {
        // ---- LDS-transpose epilogue: stats in regs, Y1 rows out as 512B bursts
        unsigned short* Tr = Asm;          // 32 rows x TLD bf16 = 16.9 KB
        float w1bf[4], sAcc[4] = {0.f,0.f,0.f,0.f}, qAcc[4] = {0.f,0.f,0.f,0.f};
#pragma unroll
        for (int f = 0; f < 4; f++)
            w1bf[f] = W1[(size_t)128 * LSZ + ((wave * 4 + f) << 4) + l15];

        __syncthreads();                   // all MFMA reads of Asm done
#pragma unroll
        for (int pass = 0; pass < 2; pass++) {
            if (pass) __syncthreads();     // pass0 reads done before overwrite
#pragma unroll
            for (int mfl = 0; mfl < 2; mfl++) {
                const int mf = pass * 2 + mfl;
#pragma unroll
                for (int f = 0; f < 4; f++) {
                    const int col = ((wave * 4 + f) << 4) + l15;
#pragma unroll
                    for (int r = 0; r < 4; r++) {
                        float y = fmaf(bv[mf][r], w1bf[f], acc[mf][f][r]);
                        sAcc[f] += y; qAcc[f] += y * y;
                        Tr[(mfl * 16 + quad * 4 + r) * TLD + col] = f2bf(y);
                    }
                }
            }
            __syncthreads();
            // 32 rows x 512B out; wave-instr = 2 rows x 512B contiguous
#pragma unroll
            for (int it = 0; it < 4; it++) {
                int chunk = it * 256 + tid;        // 0..1023
                int rl = chunk >> 5, c16 = chunk & 31;
                int grow = destS[pass * 32 + rl];
                uint4 v = *(const uint4*)&Tr[rl * TLD + c16 * 8];
                *(uint4*)&y1c[(size_t)grow * LSZ + c16 * 8] = v;
            }
        }
        const int bucket = blockIdx.x & 63;
#pragma unroll
        for (int f = 0; f < 4; f++) {
            const int col = ((wave * 4 + f) << 4) + l15;
            float s = sAcc[f], q = qAcc[f];
            s += __shfl_xor(s, 16); s += __shfl_xor(s, 32);
            q += __shfl_xor(q, 16); q += __shfl_xor(q, 32);
            if (quad == 0) {
                atomicAdd(&colsum_b[bucket * LSZ + col], s);
                atomicAdd(&colsq_b [bucket * LSZ + col], q);
            }
        }
    } else {
        int dd[4][4];
#pragma unroll
        for (int mf = 0; mf < 4; mf++)
#pragma unroll
            for (int r = 0; r < 4; r++) dd[mf][r] = destS[mf * 16 + quad * 4 + r];
#pragma unroll
        for (int f = 0; f < 4; f++) {
            const int col = ((wave * 4 + f) << 4) + l15;
            const float w1b = W1[(size_t)128 * LSZ + col];
            const float Ac = a1[col], Bc = b1n[col];
#pragma unroll
            for (int mf = 0; mf < 4; mf++) {
                int cur = dd[mf][0];
                float run = fmaxf(fmaf(fmaf(bv[mf][0], w1b, acc[mf][f][0]), Ac, Bc), 0.f);
#pragma unroll
                for (int r = 1; r < 4; r++) {
                    float y = fmaxf(fmaf(fmaf(bv[mf][r], w1b, acc[mf][f][r]), Ac, Bc), 0.f);
                    if (dd[mf][r] != cur) {
                        atomicAdd(&aggsum[(size_t)cur * LSZ + col], run);
                        cur = dd[mf][r]; run = y;
                    } else run += y;
                }
                atomicAdd(&aggsum[(size_t)cur * LSZ + col], run);
            }
        }
    }
}

// ===========================================================================
// aggregate: agg[n,c] = mean over CSR slots p of relu(a1[c]*Y1c[p,c] + b1n[c])
// One WAVE per node; lane owns 4 cols (uint2 = 8B) -> each slot read is one
// fully-coalesced 512B wave load. 4 slots in flight. 50000 waves of TLP.
// Division by cnt folded in; zero atomics.
// ===========================================================================
__global__ __launch_bounds__(256, 8) void aggregate_kernel(
    const unsigned short* __restrict__ Y1c, const int* __restrict__ start,
    const float* __restrict__ a1, const float* __restrict__ b1n,
    float* __restrict__ agg)
{
    const int gw = blockIdx.x * 4 + (threadIdx.x >> 6);   // node id
    if (gw >= NN) return;
    const int lane = threadIdx.x & 63;
    const int c0 = lane << 2;                             // 4 cols per lane
    const float4 av = *(const float4*)&a1[c0];
    const float4 bv = *(const float4*)&b1n[c0];
    const int p = start[gw], p1 = start[gw + 1];
    float a0 = 0.f, a1r = 0.f, a2r = 0.f, a3r = 0.f;
    const int sm = p1 - 1;
    for (int q = p; q < p1; q += 4) {
        uint2 v[4];
#pragma unroll
        for (int j = 0; j < 4; j++) {
            int s = min(q + j, sm);
            v[j] = *(const uint2*)&Y1c[(size_t)s * LSZ + c0];
        }
#pragma unroll
        for (int j = 0; j < 4; j++) {
            if (q + j < p1) {
                unsigned lo = v[j].x, hi = v[j].y;
                a0  += fmaxf(fmaf(bf2f((unsigned short)(lo & 0xffff)), av.x, bv.x), 0.f);
                a1r += fmaxf(fmaf(bf2f((unsigned short)(lo >> 16)),    av.y, bv.y), 0.f);
                a2r += fmaxf(fmaf(bf2f((unsigned short)(hi & 0xffff)), av.z, bv.z), 0.f);
                a3r += fmaxf(fmaf(bf2f((unsigned short)(hi >> 16)),    av.w, bv.w), 0.f);
            }
        }
    }
    const float inv = 1.0f / fmaxf((float)(p1 - p), 1.0f);
    float4 o = {a0 * inv, a1r * inv, a2r * inv, a3r * inv};
    *(float4*)&agg[(size_t)gw * LSZ + c0] = o;
}

// ---------------------------------------------------------------------------
// finalize layer-1 BN: reduce 64 buckets, fold gamma/beta into affine a,b
// ---------------------------------------------------------------------------
__global__ void finalize1_kernel(
    const float* __restrict__ colsum_b, const float* __restrict__ colsq_b,
    const float* __restrict__ gamma, const float* __restrict__ beta,
    float* __restrict__ a, float* __restrict__ b)
{
    int c = threadIdx.x;  // 256
    float s = 0.f, q = 0.f;
    for (int bk = 0; bk < 64; bk++) {
        s += colsum_b[bk * LSZ + c];
        q += colsq_b [bk * LSZ + c];
    }
    float mu  = s * (1.0f / NE);
    float var = fmaxf(q * (1.0f / NE) - mu * mu, 0.f);
    float sc  = gamma[c] * rsqrtf(var + BN_EPS);
    a[c] = sc;
    b[c] = beta[c] - mu * sc;
}

// ---------------------------------------------------------------------------
// finalize layer-2 BN: reduce 64 buckets (stride Y2S), affine a2,b2n
// ---------------------------------------------------------------------------
__global__ void finalize2_kernel(
    const float* __restrict__ colsum_b, const float* __restrict__ colsq_b,
    const float* __restrict__ gamma, const float* __restrict__ beta,
    float* __restrict__ a, float* __restrict__ b)
{
    int c = blockIdx.x * 256 + threadIdx.x;
    if (c >= D2) return;
    float s = 0.f, q = 0.f;
    for (int bk = 0; bk < 64; bk++) {
        s += colsum_b[bk * Y2S + c];
        q += colsq_b [bk * Y2S + c];
    }
    float mu  = s * (1.0f / NN);
    float var = fmaxf(q * (1.0f / NN) - mu * mu, 0.f);
    float sc  = gamma[c] * rsqrtf(var + BN_EPS);
    a[c] = sc;
    b[c] = beta[c] - mu * sc;
}

// ---------------------------------------------------------------------------
// CSR build: fused dual histogram (dest from colE, source from rowE),
// dual single-block scan, fused fill producing eS/pS (fast path) or
// eidx/pos (fallback).
// ---------------------------------------------------------------------------
__global__ void hist2_kernel(const int* __restrict__ ei,
                             int* __restrict__ cntd, int* __restrict__ cnts)
{
    int t = blockIdx.x * 256 + threadIdx.x;
    if (t < NE)            atomicAdd(&cnts[ei[t]], 1);   // rowE -> source
    else if (t < 2 * NE)   atomicAdd(&cntd[ei[t]], 1);   // colE -> dest
}

__global__ __launch_bounds__(1024) void scan_kernel(
    const int* __restrict__ cA, int* __restrict__ sA,
    const int* __restrict__ cB, int* __restrict__ sB, int n)
{
    const int* cnt = blockIdx.x ? cB : cA;
    int* start     = blockIdx.x ? sB : sA;
    __shared__ int wsum[16];
    __shared__ int carry_s;
    int tid = threadIdx.x;
    if (tid == 0) { carry_s = 0; start[0] = 0; }
    __syncthreads();
    for (int base = 0; base < n; base += 1024) {
        int i = base + tid;
        int v = (i < n) ? cnt[i] : 0;
        int lane = tid & 63, wave = tid >> 6;
        int sv = v;
#pragma unroll
        for (int off = 1; off < 64; off <<= 1) {
            int t = __shfl_up(sv, off);
            if (lane >= off) sv += t;
        }
        __syncthreads();
        if (lane == 63) wsum[wave] = sv;
        __syncthreads();
        int carry = carry_s;
        int woff = carry;
        for (int w = 0; w < wave; w++) woff += wsum[w];
        int incl = sv + woff;
        if (i < n) start[i + 1] = incl;
        int total = carry;
#pragma unroll
        for (int w = 0; w < 16; w++) total += wsum[w];
        __syncthreads();
        if (tid == 0) carry_s = total;
    }
}

// fast path: for each edge, claim a dest slot pd and a source slot ps;
// record at the SOURCE slot: which edge it is (eS) and where it lands (pS).
__global__ void fill_both_kernel(
    const int* __restrict__ rowE, const int* __restrict__ colE,
    const int* __restrict__ startd, int* __restrict__ cursord,
    const int* __restrict__ starts, int* __restrict__ cursors,
    int* __restrict__ eS, int* __restrict__ pS)
{
    int e = blockIdx.x * 256 + threadIdx.x;
    if (e < NE) {
        int cd = colE[e], cs = rowE[e];
        int pd = startd[cd] + atomicAdd(&cursord[cd], 1);
        int ps = starts[cs] + atomicAdd(&cursors[cs], 1);
        eS[ps] = e;
        pS[ps] = pd;
    }
}

// fallback path fill (dest CSR only)
__global__ void fill_kernel(const int* __restrict__ colE, const int* __restrict__ start,
                            int* __restrict__ cursor, int* __restrict__ eidx,
                            int* __restrict__ pos)
{
    int e = blockIdx.x * 256 + threadIdx.x;
    if (e < NE) {
        int c = colE[e];
        int p = start[c] + atomicAdd(&cursor[c], 1);
        eidx[p] = e;
        pos[e] = p;
    }
}

// ---------------------------------------------------------------------------
// agg[n,c] = aggsum[n,c] / max(cnt[n],1)   (in-place, float4) — fallback only
// ---------------------------------------------------------------------------
__global__ __launch_bounds__(256) void divcnt_kernel(
    float* __restrict__ agg, const int* __restrict__ cnt)
{
    int f = blockIdx.x * 256 + threadIdx.x;
    int n = f >> 6;                       // 64 float4 per 256-col row
    if (n < NN) {
        float inv = 1.0f / fmaxf((float)cnt[n], 1.0f);
        float4* p = (float4*)agg + f;
        float4 v = *p;
        v.x *= inv; v.y *= inv; v.z *= inv; v.w *= inv;
        *p = v;
    }
}

// ===========================================================================
// GEMM2 (MFMA): Y2[n,c] = h2[n,:]·W2[:,c], batch rank-1 in epilogue,
// BN stats fused (bucketed col sum/sumsq). K = 384 (x 128 | agg 256).
// N padded to 416 (26 frags); grid.y in {0,1}. Y2 stored bf16, stride 416.
// ===========================================================================
__global__ __launch_bounds__(256, 3) void gemm2_mfma(
    const float* __restrict__ x, const int* __restrict__ batch,
    const float* __restrict__ agg, const float* __restrict__ W2,
    const unsigned short* __restrict__ W2p, unsigned short* __restrict__ Y2,
    float* __restrict__ colsum2_b, float* __restrict__ colsq2_b)
{
    __shared__ float bvalS[64];
    const int tid = threadIdx.x;
    const int lane = tid & 63, wave = tid >> 6;
    const int quad = lane >> 4, l15 = lane & 15;
    const int n0 = blockIdx.x * 64;
    const int fbase = blockIdx.y * 16 + wave * 4;

    if (tid < 64) bvalS[tid] = (float)batch[min(n0 + tid, NN - 1)];
    __syncthreads();

    int rn[4];
#pragma unroll
    for (int mf = 0; mf < 4; mf++) rn[mf] = min(n0 + mf * 16 + l15, NN - 1);

    const s16x8* Bp = (const s16x8*)W2p;
    f32x4 acc[4][4];
#pragma unroll
    for (int mf = 0; mf < 4; mf++)
#pragma unroll
        for (int f = 0; f < 4; f++) acc[mf][f] = (f32x4){0.f, 0.f, 0.f, 0.f};

    s16x8 bcur[4], bnxt[4];
#pragma unroll
    for (int f = 0; f < 4; f++)
        if (fbase + f < 26) bcur[f] = Bp[(size_t)(fbase + f) * 64 + lane];

#pragma unroll
    for (int s = 0; s < 12; s++) {
        if (s < 11) {
#pragma unroll
            for (int f = 0; f < 4; f++)
                if (fbase + f < 26)
                    bnxt[f] = Bp[(size_t)((s + 1) * 26 + fbase + f) * 64 + lane];
        }
        s16x8 af[4];
#pragma unroll
        for (int mf = 0; mf < 4; mf++) {
            const float* src = (s < 4)
                ? (x   + (size_t)rn[mf] * NF  + s * 32 + quad * 8)
                : (agg + (size_t)rn[mf] * LSZ + (s - 4) * 32 + quad * 8);
            float4 v0 = ((const float4*)src)[0];
            float4 v1 = ((const float4*)src)[1];
            af[mf][0] = (short)f2bf(v0.x); af[mf][1] = (short)f2bf(v0.y);
            af[mf][2] = (short)f2bf(v0.z); af[mf][3] = (short)f2bf(v0.w);
            af[mf][4] = (short)f2bf(v1.x); af[mf][5] = (short)f2bf(v1.y);
            af[mf][6] = (short)f2bf(v1.z); af[mf][7] = (short)f2bf(v1.w);
        }
#pragma unroll
        for (int mf = 0; mf < 4; mf++)
#pragma unroll
            for (int f = 0; f < 4; f++)
                if (fbase + f < 26)
                    acc[mf][f] = __builtin_amdgcn_mfma_f32_16x16x32_bf16(
                        af[mf], bcur[f], acc[mf][f], 0, 0, 0);
#pragma unroll
        for (int f = 0; f < 4; f++) bcur[f] = bnxt[f];
    }

    float bv[4][4];
#pragma unroll
    for (int mf = 0; mf < 4; mf++)
#pragma unroll
        for (int r = 0; r < 4; r++) bv[mf][r] = bvalS[mf * 16 + quad * 4 + r];

    const int bucket = blockIdx.x & 63;
#pragma unroll
    for (int f = 0; f < 4; f++) {
        int i = fbase + f;
        if (i < 26) {
            const int col = (i << 4) + l15;
            const float w2b = (col < D2) ? W2[(size_t)128 * D2 + col] : 0.f;
            float s = 0.f, q = 0.f;
#pragma unroll
            for (int mf = 0; mf < 4; mf++)
#pragma unroll
                for (int r = 0; r < 4; r++) {
                    int n = n0 + mf * 16 + quad * 4 + r;
                    if (n < NN) {
                        float y = fmaf(bv[mf][r], w2b, acc[mf][f][r]);
                        Y2[(size_t)n * Y2S + col] = f2bf(y);
                        s += y; q += y * y;
                    }
                }
            s += __shfl_xor(s, 16); s += __shfl_xor(s, 32);
            q += __shfl_xor(q, 16); q += __shfl_xor(q, 32);
            if (quad == 0) {
                atomicAdd(&colsum2_b[bucket * Y2S + col], s);
                atomicAdd(&colsq2_b [bucket * Y2S + col], q);
            }
        }
    }
}

// ===========================================================================
// GEMM3 (MFMA): out[n,c] = relu( relu(a2⊙Y2[n,:]+b2n)·W3[:,c] + b3[c] )
// K = 416 (13 steps; pads have a2=b2n=0 -> A=0). N = 128 = 8 frags.
// ===========================================================================
__global__ __launch_bounds__(256, 3) void gemm3_mfma(
    const unsigned short* __restrict__ Y2, const float* __restrict__ a2,
    const float* __restrict__ b2n, const unsigned short* __restrict__ W3p,
    const float* __restrict__ b3, float* __restrict__ out)
{
    const int tid = threadIdx.x;
    const int lane = tid & 63, wave = tid >> 6;
    const int quad = lane >> 4, l15 = lane & 15;
    const int n0 = blockIdx.x * 64;

    int rn[4];
#pragma unroll
    for (int mf = 0; mf < 4; mf++) rn[mf] = min(n0 + mf * 16 + l15, NN - 1);

    const s16x8* Bp = (const s16x8*)W3p;
    f32x4 acc[4][2];
#pragma unroll
    for (int mf = 0; mf < 4; mf++)
#pragma unroll
        for (int f = 0; f < 2; f++) acc[mf][f] = (f32x4){0.f, 0.f, 0.f, 0.f};

    s16x8 bcur[2], bnxt[2];
#pragma unroll
    for (int f = 0; f < 2; f++)
        bcur[f] = Bp[(size_t)(wave * 2 + f) * 64 + lane];

#pragma unroll
    for (int s = 0; s < 13; s++) {
        if (s < 12) {
#pragma unroll
            for (int f = 0; f < 2; f++)
                bnxt[f] = Bp[(size_t)((s + 1) * 8 + wave * 2 + f) * 64 + lane];
        }
        const int kb = s * 32 + quad * 8;
        float4 A0 = *(const float4*)&a2[kb],  A1 = *(const float4*)&a2[kb + 4];
        float4 B0 = *(const float4*)&b2n[kb], B1 = *(const float4*)&b2n[kb + 4];
        float Aj[8] = {A0.x, A0.y, A0.z, A0.w, A1.x, A1.y, A1.z, A1.w};
        float Bj[8] = {B0.x, B0.y, B0.z, B0.w, B1.x, B1.y, B1.z, B1.w};
#pragma unroll
        for (int mf = 0; mf < 4; mf++) {
            s16x8 yv = *(const s16x8*)&Y2[(size_t)rn[mf] * Y2S + kb];
            s16x8 af;
#pragma unroll
            for (int j = 0; j < 8; j++) {
                float y = bf2f((unsigned short)yv[j]);
                y = fmaxf(fmaf(y, Aj[j], Bj[j]), 0.f);
                af[j] = (short)f2bf(y);
            }
#pragma unroll
            for (int f = 0; f < 2; f++)
                acc[mf][f] = __builtin_amdgcn_mfma_f32_16x16x32_bf16(
                    af, bcur[f], acc[mf][f], 0, 0, 0);
        }
#pragma unroll
        for (int f = 0; f < 2; f++) bcur[f] = bnxt[f];
    }

#pragma unroll
    for (int f = 0; f < 2; f++) {
        const int col = ((wave * 2 + f) << 4) + l15;
        const float bb = b3[col];
#pragma unroll
        for (int mf = 0; mf < 4; mf++)
#pragma unroll
            for (int r = 0; r < 4; r++) {
                int n = n0 + mf * 16 + quad * 4 + r;
                if (n < NN)
                    out[(size_t)n * NF + col] = fmaxf(acc[mf][f][r] + bb, 0.f);
            }
    }
}

// ---------------------------------------------------------------------------
extern "C" void kernel_launch(void* const* d_in, const int* in_sizes, int n_in,
                              void* d_out, int out_size, void* d_ws, size_t ws_size,
                              hipStream_t stream)
{
    const float* x         = (const float*)d_in[0];
    const int*   edge_idx  = (const int*)d_in[1];
    const float* edge_attr = (const float*)d_in[2];
    // d_in[3] = u : unused by the reference
    const int*   batch     = (const int*)d_in[4];
    const float* W1        = (const float*)d_in[5];
    // d_in[6] = b1 : cancelled by BatchNorm
    const float* g1        = (const float*)d_in[7];
    const float* be1       = (const float*)d_in[8];
    const float* W2        = (const float*)d_in[9];
    // d_in[10] = b2 : cancelled by BatchNorm
    const float* g2        = (const float*)d_in[11];
    const float* be2       = (const float*)d_in[12];
    const float* W3        = (const float*)d_in[13];
    const float* b3        = (const float*)d_in[14];
    float* out = (float*)d_out;

    const int* rowE = edge_idx;        // edge_index[0]
    const int* colE = edge_idx + NE;   // edge_index[1]

    // ---- workspace layout ----
    // eS/pS (fast path, source-CSR) alias eidx/pos (fallback) — never both.
    // Y1 (CSR-dest-ordered bf16, NE x 256 = 409.6 MB) aliases Y2 and extends
    // past the base total; Y1 dies before gemm2 writes Y2.
    char* ws = (char*)d_ws;
    size_t off = 0;
    auto alloc = [&](size_t bytes) -> void* {
        void* p = ws + off;
        off += (bytes + 255) & ~(size_t)255;
        return p;
    };
    int*            eidx = (int*)alloc((size_t)NE * 4);     // = eS (fast path)
    int*            pos  = (int*)alloc((size_t)NE * 4);     // = pS (fast path)
    int*            start= (int*)alloc((size_t)(NN + 1) * 4);   // dest CSR
    int*            start2=(int*)alloc((size_t)(NN + 1) * 4);   // source CSR
    float*          a1   = (float*)alloc(LSZ * 4);
    float*          b1n  = (float*)alloc(LSZ * 4);
    unsigned short* W1p  = (unsigned short*)alloc((size_t)6  * 16 * 64 * 8 * 2); //  96 KB
    unsigned short* W2p  = (unsigned short*)alloc((size_t)12 * 26 * 64 * 8 * 2); // 312 KB
    unsigned short* W3p  = (unsigned short*)alloc((size_t)13 * 8  * 64 * 8 * 2); // 104 KB
    size_t zoff = off;                                             // ---- zero region ----
    int*   cnt       = (int*)  alloc((size_t)NN * 4);
    int*   cursor    = (int*)  alloc((size_t)NN * 4);
    int*   cnt2      = (int*)  alloc((size_t)NN * 4);
    int*   cursor2   = (int*)  alloc((size_t)NN * 4);
    float* colsum_b  = (float*)alloc(64 * LSZ * 4);
    float* colsq_b   = (float*)alloc(64 * LSZ * 4);
    float* colsum2_b = (float*)alloc(64 * Y2S * 4);                // 106 KB
    float* colsq2_b  = (float*)alloc(64 * Y2S * 4);
    float* a2        = (float*)alloc(Y2S * 4);   // pads (>=385) must stay 0
    float* b2n       = (float*)alloc(Y2S * 4);
    size_t zend = off;                                             // ---- end zero ----
    float* agg       = (float*)alloc((size_t)NN * LSZ * 4);        // 51.2 MB
    size_t y2off = off;
    unsigned short* Y2 = (unsigned short*)alloc((size_t)NN * Y2S * 2);    // 41.6 MB
    size_t total_base = off;
    size_t total_y1   = y2off + (size_t)NE * LSZ * 2;              // Y1 over Y2 + tail
    if (ws_size < total_base) return;
    const bool use_y1 = (ws_size >= total_y1);
    unsigned short* Y1 = (unsigned short*)(ws + y2off);

    hipMemsetAsync(ws + zoff, 0, zend - zoff, stream);
    if (!use_y1)
        hipMemsetAsync(agg, 0, (size_t)NN * LSZ * 4, stream);

    // weight pre-pack into fragment order (rank-1 batch row skipped for W1/W2)
    prep_w_kernel<<<(6  * 16 * 64 + 255) / 256, 256, 0, stream>>>(W1, LSZ, LSZ, D1, 128, 16, 6,  W1p);
    prep_w_kernel<<<(12 * 26 * 64 + 255) / 256, 256, 0, stream>>>(W2, D2,  D2,  D2, 128, 26, 12, W2p);
    prep_w_kernel<<<(13 * 8  * 64 + 255) / 256, 256, 0, stream>>>(W3, NF,  NF,  D2, -1,  8,  13, W3p);

    // dual CSR build: dest (aggregation ranges) + source (edge processing order)
    hist2_kernel<<<(2 * NE) / 256, 256, 0, stream>>>(edge_idx, cnt, cnt2);
    scan_kernel<<<2, 1024, 0, stream>>>(cnt, start, cnt2, start2, NN);

    if (use_y1) {
        fill_both_kernel<<<NE / 256, 256, 0, stream>>>(
            rowE, colE, start, cursor, start2, cursor2, eidx /*eS*/, pos /*pS*/);
        // single edge-MLP pass in SOURCE order: GEMM + BN stats + Y1 at dest slot
        gemm1_mfma<2><<<NE / 64, 256, 0, stream>>>(
            x, rowE, eidx /*eS*/, batch, edge_attr, W1, W1p,
            pos /*pS*/, nullptr, nullptr, colsum_b, colsq_b, nullptr, Y1);
        finalize1_kernel<<<1, 256, 0, stream>>>(colsum_b, colsq_b, g1, be1, a1, b1n);
        // atomic-free streaming reduce over CSR ranges (mean folded in)
        aggregate_kernel<<<(NN + 3) / 4, 256, 0, stream>>>(Y1, start, a1, b1n, agg);
    } else {
        // fallback: original two-pass recompute + scatter-atomic path
        fill_kernel<<<NE / 256, 256, 0, stream>>>(colE, start, cursor, eidx, pos);
        gemm1_mfma<0><<<NE / 64, 256, 0, stream>>>(
            x, rowE, colE, batch, edge_attr, W1, W1p,
            nullptr, nullptr, nullptr, colsum_b, colsq_b, nullptr, nullptr);
        finalize1_kernel<<<1, 256, 0, stream>>>(colsum_b, colsq_b, g1, be1, a1, b1n);
        gemm1_mfma<1><<<NE / 64, 256, 0, stream>>>(
            x, rowE, colE, batch, edge_attr, W1, W1p,
            eidx, a1, b1n, nullptr, nullptr, agg, nullptr);
        divcnt_kernel<<<(NN * LSZ / 4) / 256, 256, 0, stream>>>(agg, cnt);
    }

    // node MLP (MFMA, bf16 Y2, fused BN stats)
    gemm2_mfma<<<dim3((NN + 63) / 64, 2), 256, 0, stream>>>(
        x, batch, agg, W2, W2p, Y2, colsum2_b, colsq2_b);
    finalize2_kernel<<<2, 256, 0, stream>>>(colsum2_b, colsq2_b, g2, be2, a2, b2n);

    // output linear (MFMA, BN affine + ReLU fused into A build)
    gemm3_mfma<<<(NN + 63) / 64, 256, 0, stream>>>(Y2, a2, b2n, W3p, b3, out);
}

// Round 4
// 909.111 us; speedup vs baseline: 1.2734x; 1.2734x over previous
//
#include <hip/hip_runtime.h>

#define NN 50000      // nodes
#define NE 800000     // edges
#define NF 128        // node features
#define EF 64         // edge features
#define LSZ 256       // layer size
#define D1 193        // NF+EF+1
#define D2 385        // NF+LSZ+1
#define Y2S 416       // Y2 row stride = 13*32 (gemm3 K, padded)
#define ALD 208       // gemm1 LDS A row stride (bf16 elems)
#define TLD 264       // gemm1 LDS transpose row stride (bf16, 528B: 2-way only)
#define BN_EPS 1e-5f

typedef float f32x4 __attribute__((ext_vector_type(4)));
typedef short s16x8 __attribute__((ext_vector_type(8)));

__device__ __forceinline__ unsigned short f2bf(float f) {
    unsigned u = __float_as_uint(f);
    u += 0x7FFFu + ((u >> 16) & 1u);   // RNE
    return (unsigned short)(u >> 16);
}
__device__ __forceinline__ float bf2f(unsigned short s) {
    return __uint_as_float(((unsigned)s) << 16);
}

// ===========================================================================
// Generic weight pre-pack into MFMA B-fragment order.
// Fragment (s, i): k' = s*32 + (lane>>4)*8 + j ; col n = 16*i + (lane&15).
// Source row = k' (or k'+1 if k' >= batch_row, skipping the rank-1 batch row).
// ===========================================================================
__global__ void prep_w_kernel(const float* __restrict__ W, int ldw, int ncols,
                              int kmax_src, int batch_row, int nfrag, int ksteps,
                              unsigned short* __restrict__ Wp)
{
    int t = blockIdx.x * 256 + threadIdx.x;
    if (t >= ksteps * nfrag * 64) return;
    int lane = t & 63, si = t >> 6;
    int i = si % nfrag, s = si / nfrag;
    int q = lane >> 4, n = (i << 4) + (lane & 15);
    unsigned short v[8];
#pragma unroll
    for (int j = 0; j < 8; j++) {
        int k = s * 32 + q * 8 + j;
        int sr = (batch_row >= 0 && k >= batch_row) ? k + 1 : k;
        v[j] = (sr < kmax_src && n < ncols) ? f2bf(W[(size_t)sr * ldw + n])
                                            : (unsigned short)0;
    }
    *(uint4*)&Wp[(size_t)t * 8] = *(const uint4*)v;
}

// ===========================================================================
// GEMM1: block = 64 edges x 256 cols, 4 waves; wave owns 64 cols (4 N-frags).
// K = 192; batch column applied rank-1 in epilogue.
// A staged through LDS with coalesced row bursts (bf16), B double-buffered.
// MODE 0: BN stats only (bucketed col sum/sumsq)            [fallback]
// MODE 1: CSR order, affine+ReLU, scatter-atomic into aggsum [fallback]
// MODE 2: NATURAL edge order (sequential edge_attr reads — proven optimal;
//         source-sorted variant regressed: FETCH+WRITE amplification at
//         pattern-limited ~3.4 TB/s).  BN stats in regs + Y1 written at CSR
//         position pos[e] via LDS transpose as 512B full-row bursts.
// ===========================================================================
template <int MODE>
__global__ __launch_bounds__(256, 4) void gemm1_mfma(
    const float* __restrict__ x, const int* __restrict__ rowi,
    const int* __restrict__ colE, const int* __restrict__ batch,
    const float* __restrict__ ea, const float* __restrict__ W1,
    const unsigned short* __restrict__ W1p, const int* __restrict__ eidx,
    const float* __restrict__ a1, const float* __restrict__ b1n,
    float* __restrict__ colsum_b, float* __restrict__ colsq_b,
    float* __restrict__ aggsum, unsigned short* __restrict__ y1c)
{
    __shared__ unsigned short Asm[64 * ALD];   // 26.6 KB; reused as transpose buf
    __shared__ int   rowS[64];
    __shared__ int   eSs[64];
    __shared__ float bvalS[64];
    __shared__ int   destS[64];

    const int tid = threadIdx.x;
    const int lane = tid & 63, wave = tid >> 6;
    const int quad = lane >> 4, l15 = lane & 15;
    const int e0 = blockIdx.x * 64;

    if (tid < 64) {
        int e = (MODE == 1) ? eidx[e0 + tid] : (e0 + tid);
        eSs[tid] = e;
        int r = rowi[e];
        rowS[tid] = r;
        bvalS[tid] = (float)batch[r];
        if (MODE == 1) destS[tid] = colE[e];
        if (MODE == 2) destS[tid] = eidx[e0 + tid];   // pos[e], e = e0+tid
    }
    __syncthreads();

    // ---- stage A into LDS: x = 2048 float4 (cols 0..127), ea = 1024 float4
    // (cols 128..191). Consecutive lanes -> consecutive cols of the same row:
    // full 512B/256B row bursts. 12 independent loads/thread, one wait.
#pragma unroll
    for (int i = 0; i < 12; i++) {
        int idx = i * 256 + tid;
        int row, col4;
        const float* src;
        if (idx < 2048) {                       // compile-time resolvable per i
            row = idx >> 5; col4 = idx & 31;
            src = x + (size_t)rowS[row] * NF + col4 * 4;
        } else {
            int j = idx - 2048;
            row = j >> 4; col4 = 32 + (j & 15);
            src = ea + (size_t)eSs[row] * EF + (col4 - 32) * 4;
        }
        float4 v = *(const float4*)src;
        ushort4 h;
        h.x = f2bf(v.x); h.y = f2bf(v.y); h.z = f2bf(v.z); h.w = f2bf(v.w);
        *(uint2*)&Asm[row * ALD + col4 * 4] = *(uint2*)&h;
    }
    __syncthreads();

    const s16x8* Bp = (const s16x8*)W1p;
    f32x4 acc[4][4];
#pragma unroll
    for (int mf = 0; mf < 4; mf++)
#pragma unroll
        for (int f = 0; f < 4; f++) acc[mf][f] = (f32x4){0.f, 0.f, 0.f, 0.f};

    s16x8 bcur[4], bnxt[4];
#pragma unroll
    for (int f = 0; f < 4; f++)
        bcur[f] = Bp[(size_t)(wave * 4 + f) * 64 + lane];

#pragma unroll
    for (int s = 0; s < 6; s++) {
        if (s < 5) {
#pragma unroll
            for (int f = 0; f < 4; f++)
                bnxt[f] = Bp[(size_t)((s + 1) * 16 + wave * 4 + f) * 64 + lane];
        }
        s16x8 af[4];
#pragma unroll
        for (int mf = 0; mf < 4; mf++)
            af[mf] = *(const s16x8*)&Asm[(mf * 16 + l15) * ALD + s * 32 + quad * 8];
#pragma unroll
        for (int mf = 0; mf < 4; mf++)
#pragma unroll
            for (int f = 0; f < 4; f++)
                acc[mf][f] = __builtin_amdgcn_mfma_f32_16x16x32_bf16(
                    af[mf], bcur[f], acc[mf][f], 0, 0, 0);
#pragma unroll
        for (int f = 0; f < 4; f++) bcur[f] = bnxt[f];
    }

    // C/D: element r of lane = C[row = mf*16 + quad*4 + r][col = 16*i + l15]
    float bv[4][4];
#pragma unroll
    for (int mf = 0; mf < 4; mf++)
#pragma unroll
        for (int r = 0; r < 4; r++) bv[mf][r] = bvalS[mf * 16 + quad * 4 + r];

    if (MODE == 0) {
        const int bucket = blockIdx.x & 63;
#pragma unroll
        for (int f = 0; f < 4; f++) {
            const int col = ((wave * 4 + f) << 4) + l15;
            const float w1b = W1[(size_t)128 * LSZ + col];   // rank-1 batch row
            float s = 0.f, q = 0.f;
#pragma unroll
            for (int mf = 0; mf < 4; mf++)
#pragma unroll
                for (int r = 0; r < 4; r++) {
                    float y = fmaf(bv[mf][r], w1b, acc[mf][f][r]);
                    s += y; q += y * y;
                }
            s += __shfl_xor(s, 16); s += __shfl_xor(s, 32);
            q += __shfl_xor(q, 16); q += __shfl_xor(q, 32);
            if (quad == 0) {
                atomicAdd(&colsum_b[bucket * LSZ + col], s);
                atomicAdd(&colsq_b [bucket * LSZ + col], q);
            }
        }
    } else if (MODE == 2) {
        // ---- LDS-transpose epilogue: stats in regs, Y1 rows out as 512B bursts
        unsigned short* Tr = Asm;          // 32 rows x TLD bf16 = 16.9 KB
        float w1bf[4], sAcc[4] = {0.f,0.f,0.f,0.f}, qAcc[4] = {0.f,0.f,0.f,0.f};
#pragma unroll
        for (int f = 0; f < 4; f++)
            w1bf[f] = W1[(size_t)128 * LSZ + ((wave * 4 + f) << 4) + l15];

        __syncthreads();                   // all MFMA reads of Asm done
#pragma unroll
        for (int pass = 0; pass < 2; pass++) {
            if (pass) __syncthreads();     // pass0 reads done before overwrite
#pragma unroll
            for (int mfl = 0; mfl < 2; mfl++) {
                const int mf = pass * 2 + mfl;
#pragma unroll
                for (int f = 0; f < 4; f++) {
                    const int col = ((wave * 4 + f) << 4) + l15;
#pragma unroll
                    for (int r = 0; r < 4; r++) {
                        float y = fmaf(bv[mf][r], w1bf[f], acc[mf][f][r]);
                        sAcc[f] += y; qAcc[f] += y * y;
                        Tr[(mfl * 16 + quad * 4 + r) * TLD + col] = f2bf(y);
                    }
                }
            }
            __syncthreads();
            // 32 rows x 512B out; wave-instr = 2 rows x 512B contiguous
#pragma unroll
            for (int it = 0; it < 4; it++) {
                int chunk = it * 256 + tid;        // 0..1023
                int rl = chunk >> 5, c16 = chunk & 31;
                int grow = destS[pass * 32 + rl];
                uint4 v = *(const uint4*)&Tr[rl * TLD + c16 * 8];
                *(uint4*)&y1c[(size_t)grow * LSZ + c16 * 8] = v;
            }
        }
        const int bucket = blockIdx.x & 63;
#pragma unroll
        for (int f = 0; f < 4; f++) {
            const int col = ((wave * 4 + f) << 4) + l15;
            float s = sAcc[f], q = qAcc[f];
            s += __shfl_xor(s, 16); s += __shfl_xor(s, 32);
            q += __shfl_xor(q, 16); q += __shfl_xor(q, 32);
            if (quad == 0) {
                atomicAdd(&colsum_b[bucket * LSZ + col], s);
                atomicAdd(&colsq_b [bucket * LSZ + col], q);
            }
        }
    } else {
        int dd[4][4];
#pragma unroll
        for (int mf = 0; mf < 4; mf++)
#pragma unroll
            for (int r = 0; r < 4; r++) dd[mf][r] = destS[mf * 16 + quad * 4 + r];
#pragma unroll
        for (int f = 0; f < 4; f++) {
            const int col = ((wave * 4 + f) << 4) + l15;
            const float w1b = W1[(size_t)128 * LSZ + col];
            const float Ac = a1[col], Bc = b1n[col];
#pragma unroll
            for (int mf = 0; mf < 4; mf++) {
                int cur = dd[mf][0];
                float run = fmaxf(fmaf(fmaf(bv[mf][0], w1b, acc[mf][f][0]), Ac, Bc), 0.f);
#pragma unroll
                for (int r = 1; r < 4; r++) {
                    float y = fmaxf(fmaf(fmaf(bv[mf][r], w1b, acc[mf][f][r]), Ac, Bc), 0.f);
                    if (dd[mf][r] != cur) {
                        atomicAdd(&aggsum[(size_t)cur * LSZ + col], run);
                        cur = dd[mf][r]; run = y;
                    } else run += y;
                }
                atomicAdd(&aggsum[(size_t)cur * LSZ + col], run);
            }
        }
    }
}

// ===========================================================================
// aggregate: agg[n,c] = mean over CSR slots p of relu(a1[c]*Y1c[p,c] + b1n[c])
// One WAVE per node; lane owns 4 cols (uint2 = 8B) -> each slot read is one
// fully-coalesced 512B wave load. 4 slots in flight. 50000 waves of TLP.
// Division by cnt folded in; zero atomics.
// ===========================================================================
__global__ __launch_bounds__(256, 8) void aggregate_kernel(
    const unsigned short* __restrict__ Y1c, const int* __restrict__ start,
    const float* __restrict__ a1, const float* __restrict__ b1n,
    float* __restrict__ agg)
{
    const int gw = blockIdx.x * 4 + (threadIdx.x >> 6);   // node id
    if (gw >= NN) return;
    const int lane = threadIdx.x & 63;
    const int c0 = lane << 2;                             // 4 cols per lane
    const float4 av = *(const float4*)&a1[c0];
    const float4 bv = *(const float4*)&b1n[c0];
    const int p = start[gw], p1 = start[gw + 1];
    float a0 = 0.f, a1r = 0.f, a2r = 0.f, a3r = 0.f;
    const int sm = p1 - 1;
    for (int q = p; q < p1; q += 4) {
        uint2 v[4];
#pragma unroll
        for (int j = 0; j < 4; j++) {
            int s = min(q + j, sm);
            v[j] = *(const uint2*)&Y1c[(size_t)s * LSZ + c0];
        }
#pragma unroll
        for (int j = 0; j < 4; j++) {
            if (q + j < p1) {
                unsigned lo = v[j].x, hi = v[j].y;
                a0  += fmaxf(fmaf(bf2f((unsigned short)(lo & 0xffff)), av.x, bv.x), 0.f);
                a1r += fmaxf(fmaf(bf2f((unsigned short)(lo >> 16)),    av.y, bv.y), 0.f);
                a2r += fmaxf(fmaf(bf2f((unsigned short)(hi & 0xffff)), av.z, bv.z), 0.f);
                a3r += fmaxf(fmaf(bf2f((unsigned short)(hi >> 16)),    av.w, bv.w), 0.f);
            }
        }
    }
    const float inv = 1.0f / fmaxf((float)(p1 - p), 1.0f);
    float4 o = {a0 * inv, a1r * inv, a2r * inv, a3r * inv};
    *(float4*)&agg[(size_t)gw * LSZ + c0] = o;
}

// ---------------------------------------------------------------------------
// finalize layer-1 BN: reduce 64 buckets, fold gamma/beta into affine a,b
// ---------------------------------------------------------------------------
__global__ void finalize1_kernel(
    const float* __restrict__ colsum_b, const float* __restrict__ colsq_b,
    const float* __restrict__ gamma, const float* __restrict__ beta,
    float* __restrict__ a, float* __restrict__ b)
{
    int c = threadIdx.x;  // 256
    float s = 0.f, q = 0.f;
    for (int bk = 0; bk < 64; bk++) {
        s += colsum_b[bk * LSZ + c];
        q += colsq_b [bk * LSZ + c];
    }
    float mu  = s * (1.0f / NE);
    float var = fmaxf(q * (1.0f / NE) - mu * mu, 0.f);
    float sc  = gamma[c] * rsqrtf(var + BN_EPS);
    a[c] = sc;
    b[c] = beta[c] - mu * sc;
}

// ---------------------------------------------------------------------------
// finalize layer-2 BN: reduce 64 buckets (stride Y2S), affine a2,b2n
// ---------------------------------------------------------------------------
__global__ void finalize2_kernel(
    const float* __restrict__ colsum_b, const float* __restrict__ colsq_b,
    const float* __restrict__ gamma, const float* __restrict__ beta,
    float* __restrict__ a, float* __restrict__ b)
{
    int c = blockIdx.x * 256 + threadIdx.x;
    if (c >= D2) return;
    float s = 0.f, q = 0.f;
    for (int bk = 0; bk < 64; bk++) {
        s += colsum_b[bk * Y2S + c];
        q += colsq_b [bk * Y2S + c];
    }
    float mu  = s * (1.0f / NN);
    float var = fmaxf(q * (1.0f / NN) - mu * mu, 0.f);
    float sc  = gamma[c] * rsqrtf(var + BN_EPS);
    a[c] = sc;
    b[c] = beta[c] - mu * sc;
}

// ---------------------------------------------------------------------------
// CSR build: histogram, single-block scan, slot fill (also emits pos[e])
// ---------------------------------------------------------------------------
__global__ void hist_kernel(const int* __restrict__ colE, int* __restrict__ cnt)
{
    int e = blockIdx.x * 256 + threadIdx.x;
    if (e < NE) atomicAdd(&cnt[colE[e]], 1);
}

__global__ __launch_bounds__(1024) void scan_kernel(
    const int* __restrict__ cnt, int* __restrict__ start, int n)
{
    __shared__ int wsum[16];
    __shared__ int carry_s;
    int tid = threadIdx.x;
    if (tid == 0) { carry_s = 0; start[0] = 0; }
    __syncthreads();
    for (int base = 0; base < n; base += 1024) {
        int i = base + tid;
        int v = (i < n) ? cnt[i] : 0;
        int lane = tid & 63, wave = tid >> 6;
        int sv = v;
#pragma unroll
        for (int off = 1; off < 64; off <<= 1) {
            int t = __shfl_up(sv, off);
            if (lane >= off) sv += t;
        }
        __syncthreads();
        if (lane == 63) wsum[wave] = sv;
        __syncthreads();
        int carry = carry_s;
        int woff = carry;
        for (int w = 0; w < wave; w++) woff += wsum[w];
        int incl = sv + woff;
        if (i < n) start[i + 1] = incl;
        int total = carry;
#pragma unroll
        for (int w = 0; w < 16; w++) total += wsum[w];
        __syncthreads();
        if (tid == 0) carry_s = total;
    }
}

__global__ void fill_kernel(const int* __restrict__ colE, const int* __restrict__ start,
                            int* __restrict__ cursor, int* __restrict__ eidx,
                            int* __restrict__ pos)
{
    int e = blockIdx.x * 256 + threadIdx.x;
    if (e < NE) {
        int c = colE[e];
        int p = start[c] + atomicAdd(&cursor[c], 1);
        eidx[p] = e;
        pos[e] = p;
    }
}

// ---------------------------------------------------------------------------
// agg[n,c] = aggsum[n,c] / max(cnt[n],1)   (in-place, float4) — fallback only
// ---------------------------------------------------------------------------
__global__ __launch_bounds__(256) void divcnt_kernel(
    float* __restrict__ agg, const int* __restrict__ cnt)
{
    int f = blockIdx.x * 256 + threadIdx.x;
    int n = f >> 6;                       // 64 float4 per 256-col row
    if (n < NN) {
        float inv = 1.0f / fmaxf((float)cnt[n], 1.0f);
        float4* p = (float4*)agg + f;
        float4 v = *p;
        v.x *= inv; v.y *= inv; v.z *= inv; v.w *= inv;
        *p = v;
    }
}

// ===========================================================================
// GEMM2 (MFMA): Y2[n,c] = h2[n,:]·W2[:,c], batch rank-1 in epilogue,
// BN stats fused (bucketed col sum/sumsq). K = 384 (x 128 | agg 256).
// N padded to 416 (26 frags); grid.y in {0,1}. Y2 stored bf16, stride 416.
// ===========================================================================
__global__ __launch_bounds__(256, 3) void gemm2_mfma(
    const float* __restrict__ x, const int* __restrict__ batch,
    const float* __restrict__ agg, const float* __restrict__ W2,
    const unsigned short* __restrict__ W2p, unsigned short* __restrict__ Y2,
    float* __restrict__ colsum2_b, float* __restrict__ colsq2_b)
{
    __shared__ float bvalS[64];
    const int tid = threadIdx.x;
    const int lane = tid & 63, wave = tid >> 6;
    const int quad = lane >> 4, l15 = lane & 15;
    const int n0 = blockIdx.x * 64;
    const int fbase = blockIdx.y * 16 + wave * 4;

    if (tid < 64) bvalS[tid] = (float)batch[min(n0 + tid, NN - 1)];
    __syncthreads();

    int rn[4];
#pragma unroll
    for (int mf = 0; mf < 4; mf++) rn[mf] = min(n0 + mf * 16 + l15, NN - 1);

    const s16x8* Bp = (const s16x8*)W2p;
    f32x4 acc[4][4];
#pragma unroll
    for (int mf = 0; mf < 4; mf++)
#pragma unroll
        for (int f = 0; f < 4; f++) acc[mf][f] = (f32x4){0.f, 0.f, 0.f, 0.f};

    s16x8 bcur[4], bnxt[4];
#pragma unroll
    for (int f = 0; f < 4; f++)
        if (fbase + f < 26) bcur[f] = Bp[(size_t)(fbase + f) * 64 + lane];

#pragma unroll
    for (int s = 0; s < 12; s++) {
        if (s < 11) {
#pragma unroll
            for (int f = 0; f < 4; f++)
                if (fbase + f < 26)
                    bnxt[f] = Bp[(size_t)((s + 1) * 26 + fbase + f) * 64 + lane];
        }
        s16x8 af[4];
#pragma unroll
        for (int mf = 0; mf < 4; mf++) {
            const float* src = (s < 4)
                ? (x   + (size_t)rn[mf] * NF  + s * 32 + quad * 8)
                : (agg + (size_t)rn[mf] * LSZ + (s - 4) * 32 + quad * 8);
            float4 v0 = ((const float4*)src)[0];
            float4 v1 = ((const float4*)src)[1];
            af[mf][0] = (short)f2bf(v0.x); af[mf][1] = (short)f2bf(v0.y);
            af[mf][2] = (short)f2bf(v0.z); af[mf][3] = (short)f2bf(v0.w);
            af[mf][4] = (short)f2bf(v1.x); af[mf][5] = (short)f2bf(v1.y);
            af[mf][6] = (short)f2bf(v1.z); af[mf][7] = (short)f2bf(v1.w);
        }
#pragma unroll
        for (int mf = 0; mf < 4; mf++)
#pragma unroll
            for (int f = 0; f < 4; f++)
                if (fbase + f < 26)
                    acc[mf][f] = __builtin_amdgcn_mfma_f32_16x16x32_bf16(
                        af[mf], bcur[f], acc[mf][f], 0, 0, 0);
#pragma unroll
        for (int f = 0; f < 4; f++) bcur[f] = bnxt[f];
    }

    float bv[4][4];
#pragma unroll
    for (int mf = 0; mf < 4; mf++)
#pragma unroll
        for (int r = 0; r < 4; r++) bv[mf][r] = bvalS[mf * 16 + quad * 4 + r];

    const int bucket = blockIdx.x & 63;
#pragma unroll
    for (int f = 0; f < 4; f++) {
        int i = fbase + f;
        if (i < 26) {
            const int col = (i << 4) + l15;
            const float w2b = (col < D2) ? W2[(size_t)128 * D2 + col] : 0.f;
            float s = 0.f, q = 0.f;
#pragma unroll
            for (int mf = 0; mf < 4; mf++)
#pragma unroll
                for (int r = 0; r < 4; r++) {
                    int n = n0 + mf * 16 + quad * 4 + r;
                    if (n < NN) {
                        float y = fmaf(bv[mf][r], w2b, acc[mf][f][r]);
                        Y2[(size_t)n * Y2S + col] = f2bf(y);
                        s += y; q += y * y;
                    }
                }
            s += __shfl_xor(s, 16); s += __shfl_xor(s, 32);
            q += __shfl_xor(q, 16); q += __shfl_xor(q, 32);
            if (quad == 0) {
                atomicAdd(&colsum2_b[bucket * Y2S + col], s);
                atomicAdd(&colsq2_b [bucket * Y2S + col], q);
            }
        }
    }
}

// ===========================================================================
// GEMM3 (MFMA): out[n,c] = relu( relu(a2⊙Y2[n,:]+b2n)·W3[:,c] + b3[c] )
// K = 416 (13 steps; pads have a2=b2n=0 -> A=0). N = 128 = 8 frags.
// ===========================================================================
__global__ __launch_bounds__(256, 3) void gemm3_mfma(
    const unsigned short* __restrict__ Y2, const float* __restrict__ a2,
    const float* __restrict__ b2n, const unsigned short* __restrict__ W3p,
    const float* __restrict__ b3, float* __restrict__ out)
{
    const int tid = threadIdx.x;
    const int lane = tid & 63, wave = tid >> 6;
    const int quad = lane >> 4, l15 = lane & 15;
    const int n0 = blockIdx.x * 64;

    int rn[4];
#pragma unroll
    for (int mf = 0; mf < 4; mf++) rn[mf] = min(n0 + mf * 16 + l15, NN - 1);

    const s16x8* Bp = (const s16x8*)W3p;
    f32x4 acc[4][2];
#pragma unroll
    for (int mf = 0; mf < 4; mf++)
#pragma unroll
        for (int f = 0; f < 2; f++) acc[mf][f] = (f32x4){0.f, 0.f, 0.f, 0.f};

    s16x8 bcur[2], bnxt[2];
#pragma unroll
    for (int f = 0; f < 2; f++)
        bcur[f] = Bp[(size_t)(wave * 2 + f) * 64 + lane];

#pragma unroll
    for (int s = 0; s < 13; s++) {
        if (s < 12) {
#pragma unroll
            for (int f = 0; f < 2; f++)
                bnxt[f] = Bp[(size_t)((s + 1) * 8 + wave * 2 + f) * 64 + lane];
        }
        const int kb = s * 32 + quad * 8;
        float4 A0 = *(const float4*)&a2[kb],  A1 = *(const float4*)&a2[kb + 4];
        float4 B0 = *(const float4*)&b2n[kb], B1 = *(const float4*)&b2n[kb + 4];
        float Aj[8] = {A0.x, A0.y, A0.z, A0.w, A1.x, A1.y, A1.z, A1.w};
        float Bj[8] = {B0.x, B0.y, B0.z, B0.w, B1.x, B1.y, B1.z, B1.w};
#pragma unroll
        for (int mf = 0; mf < 4; mf++) {
            s16x8 yv = *(const s16x8*)&Y2[(size_t)rn[mf] * Y2S + kb];
            s16x8 af;
#pragma unroll
            for (int j = 0; j < 8; j++) {
                float y = bf2f((unsigned short)yv[j]);
                y = fmaxf(fmaf(y, Aj[j], Bj[j]), 0.f);
                af[j] = (short)f2bf(y);
            }
#pragma unroll
            for (int f = 0; f < 2; f++)
                acc[mf][f] = __builtin_amdgcn_mfma_f32_16x16x32_bf16(
                    af, bcur[f], acc[mf][f], 0, 0, 0);
        }
#pragma unroll
        for (int f = 0; f < 2; f++) bcur[f] = bnxt[f];
    }

#pragma unroll
    for (int f = 0; f < 2; f++) {
        const int col = ((wave * 2 + f) << 4) + l15;
        const float bb = b3[col];
#pragma unroll
        for (int mf = 0; mf < 4; mf++)
#pragma unroll
            for (int r = 0; r < 4; r++) {
                int n = n0 + mf * 16 + quad * 4 + r;
                if (n < NN)
                    out[(size_t)n * NF + col] = fmaxf(acc[mf][f][r] + bb, 0.f);
            }
    }
}

// ---------------------------------------------------------------------------
extern "C" void kernel_launch(void* const* d_in, const int* in_sizes, int n_in,
                              void* d_out, int out_size, void* d_ws, size_t ws_size,
                              hipStream_t stream)
{
    const float* x         = (const float*)d_in[0];
    const int*   edge_idx  = (const int*)d_in[1];
    const float* edge_attr = (const float*)d_in[2];
    // d_in[3] = u : unused by the reference
    const int*   batch     = (const int*)d_in[4];
    const float* W1        = (const float*)d_in[5];
    // d_in[6] = b1 : cancelled by BatchNorm
    const float* g1        = (const float*)d_in[7];
    const float* be1       = (const float*)d_in[8];
    const float* W2        = (const float*)d_in[9];
    // d_in[10] = b2 : cancelled by BatchNorm
    const float* g2        = (const float*)d_in[11];
    const float* be2       = (const float*)d_in[12];
    const float* W3        = (const float*)d_in[13];
    const float* b3        = (const float*)d_in[14];
    float* out = (float*)d_out;

    const int* rowE = edge_idx;        // edge_index[0]
    const int* colE = edge_idx + NE;   // edge_index[1]

    // ---- workspace layout ----
    // base (~101 MB): small stuff, agg, Y2 last.
    // Y1 path (+368 MB): Y1 (CSR-ordered bf16, NE x 256 = 409.6 MB) aliases
    // Y2 and extends past the base total; Y1 dies before gemm2 writes Y2.
    char* ws = (char*)d_ws;
    size_t off = 0;
    auto alloc = [&](size_t bytes) -> void* {
        void* p = ws + off;
        off += (bytes + 255) & ~(size_t)255;
        return p;
    };
    int*            eidx = (int*)alloc((size_t)NE * 4);                   //  3.2 MB
    int*            pos  = (int*)alloc((size_t)NE * 4);                   //  3.2 MB
    int*            start= (int*)alloc((size_t)(NN + 1) * 4);
    float*          a1   = (float*)alloc(LSZ * 4);
    float*          b1n  = (float*)alloc(LSZ * 4);
    unsigned short* W1p  = (unsigned short*)alloc((size_t)6  * 16 * 64 * 8 * 2); //  96 KB
    unsigned short* W2p  = (unsigned short*)alloc((size_t)12 * 26 * 64 * 8 * 2); // 312 KB
    unsigned short* W3p  = (unsigned short*)alloc((size_t)13 * 8  * 64 * 8 * 2); // 104 KB
    size_t zoff = off;                                             // ---- zero region ----
    int*   cnt       = (int*)  alloc((size_t)NN * 4);
    int*   cursor    = (int*)  alloc((size_t)NN * 4);
    float* colsum_b  = (float*)alloc(64 * LSZ * 4);
    float* colsq_b   = (float*)alloc(64 * LSZ * 4);
    float* colsum2_b = (float*)alloc(64 * Y2S * 4);                // 106 KB
    float* colsq2_b  = (float*)alloc(64 * Y2S * 4);
    float* a2        = (float*)alloc(Y2S * 4);   // pads (>=385) must stay 0
    float* b2n       = (float*)alloc(Y2S * 4);
    size_t zend = off;                                             // ---- end zero ----
    float* agg       = (float*)alloc((size_t)NN * LSZ * 4);        // 51.2 MB
    size_t y2off = off;
    unsigned short* Y2 = (unsigned short*)alloc((size_t)NN * Y2S * 2);    // 41.6 MB
    size_t total_base = off;
    size_t total_y1   = y2off + (size_t)NE * LSZ * 2;              // Y1 over Y2 + tail
    if (ws_size < total_base) return;
    const bool use_y1 = (ws_size >= total_y1);
    unsigned short* Y1 = (unsigned short*)(ws + y2off);

    hipMemsetAsync(ws + zoff, 0, zend - zoff, stream);
    if (!use_y1)
        hipMemsetAsync(agg, 0, (size_t)NN * LSZ * 4, stream);

    // weight pre-pack into fragment order (rank-1 batch row skipped for W1/W2)
    prep_w_kernel<<<(6  * 16 * 64 + 255) / 256, 256, 0, stream>>>(W1, LSZ, LSZ, D1, 128, 16, 6,  W1p);
    prep_w_kernel<<<(12 * 26 * 64 + 255) / 256, 256, 0, stream>>>(W2, D2,  D2,  D2, 128, 26, 12, W2p);
    prep_w_kernel<<<(13 * 8  * 64 + 255) / 256, 256, 0, stream>>>(W3, NF,  NF,  D2, -1,  8,  13, W3p);

    // CSR by destination node (+ inverse permutation pos[])
    hist_kernel<<<NE / 256, 256, 0, stream>>>(colE, cnt);
    scan_kernel<<<1, 1024, 0, stream>>>(cnt, start, NN);
    fill_kernel<<<NE / 256, 256, 0, stream>>>(colE, start, cursor, eidx, pos);

    if (use_y1) {
        // single edge-MLP pass (natural order): GEMM + BN stats + Y1 at CSR slot
        gemm1_mfma<2><<<NE / 64, 256, 0, stream>>>(
            x, rowE, nullptr, batch, edge_attr, W1, W1p,
            pos, nullptr, nullptr, colsum_b, colsq_b, nullptr, Y1);
        finalize1_kernel<<<1, 256, 0, stream>>>(colsum_b, colsq_b, g1, be1, a1, b1n);
        // atomic-free streaming reduce over CSR ranges (mean folded in)
        aggregate_kernel<<<(NN + 3) / 4, 256, 0, stream>>>(Y1, start, a1, b1n, agg);
    } else {
        // fallback: original two-pass recompute + scatter-atomic path
        gemm1_mfma<0><<<NE / 64, 256, 0, stream>>>(
            x, rowE, colE, batch, edge_attr, W1, W1p,
            nullptr, nullptr, nullptr, colsum_b, colsq_b, nullptr, nullptr);
        finalize1_kernel<<<1, 256, 0, stream>>>(colsum_b, colsq_b, g1, be1, a1, b1n);
        gemm1_mfma<1><<<NE / 64, 256, 0, stream>>>(
            x, rowE, colE, batch, edge_attr, W1, W1p,
            eidx, a1, b1n, nullptr, nullptr, agg, nullptr);
        divcnt_kernel<<<(NN * LSZ / 4) / 256, 256, 0, stream>>>(agg, cnt);
    }

    // node MLP (MFMA, bf16 Y2, fused BN stats)
    gemm2_mfma<<<dim3((NN + 63) / 64, 2), 256, 0, stream>>>(
        x, batch, agg, W2, W2p, Y2, colsum2_b, colsq2_b);
    finalize2_kernel<<<2, 256, 0, stream>>>(colsum2_b, colsq2_b, g2, be2, a2, b2n);

    // output linear (MFMA, BN affine + ReLU fused into A build)
    gemm3_mfma<<<(NN + 63) / 64, 256, 0, stream>>>(Y2, a2, b2n, W3p, b3, out);
}

// Round 6
// 856.104 us; speedup vs baseline: 1.3523x; 1.0619x over previous
//
#include <hip/hip_runtime.h>

#define NN 50000      // nodes
#define NE 800000     // edges
#define NF 128        // node features
#define EF 64         // edge features
#define LSZ 256       // layer size
#define D1 193        // NF+EF+1
#define D2 385        // NF+LSZ+1
#define Y2S 416       // Y2 row stride = 13*32 (gemm3 K, padded)
#define ALD 208       // gemm1 LDS A row stride (bf16 elems)
#define TLD 264       // gemm1 LDS transpose row stride (bf16, 528B: 2-way only)
#define BN_EPS 1e-5f

typedef float f32x4 __attribute__((ext_vector_type(4)));
typedef short s16x8 __attribute__((ext_vector_type(8)));
typedef unsigned int u32x4 __attribute__((ext_vector_type(4)));   // native vec
typedef unsigned int u32x2 __attribute__((ext_vector_type(2)));   // for nt ld/st

__device__ __forceinline__ unsigned short f2bf(float f) {
    unsigned u = __float_as_uint(f);
    u += 0x7FFFu + ((u >> 16) & 1u);   // RNE
    return (unsigned short)(u >> 16);
}
__device__ __forceinline__ float bf2f(unsigned short s) {
    return __uint_as_float(((unsigned)s) << 16);
}

// ===========================================================================
// x -> bf16 pre-pack (one-shot, streaming).  Moves the RNE conversion
// upstream of gemm1/gemm2 so they load bf16 directly (bit-identical math,
// half the gather bytes, zero staging VALU).
// ===========================================================================
__global__ __launch_bounds__(256) void cvt_x_kernel(
    const float* __restrict__ x, unsigned short* __restrict__ xb)
{
    int t = blockIdx.x * 256 + threadIdx.x;       // 8 elems/thread
    if (t >= NN * NF / 8) return;
    const float4* src = (const float4*)x + (size_t)t * 2;
    float4 v0 = src[0], v1 = src[1];
    unsigned short h[8] = {f2bf(v0.x), f2bf(v0.y), f2bf(v0.z), f2bf(v0.w),
                           f2bf(v1.x), f2bf(v1.y), f2bf(v1.z), f2bf(v1.w)};
    *(uint4*)&xb[(size_t)t * 8] = *(const uint4*)h;
}

// ===========================================================================
// Generic weight pre-pack into MFMA B-fragment order.
// Fragment (s, i): k' = s*32 + (lane>>4)*8 + j ; col n = 16*i + (lane&15).
// Source row = k' (or k'+1 if k' >= batch_row, skipping the rank-1 batch row).
// ===========================================================================
__global__ void prep_w_kernel(const float* __restrict__ W, int ldw, int ncols,
                              int kmax_src, int batch_row, int nfrag, int ksteps,
                              unsigned short* __restrict__ Wp)
{
    int t = blockIdx.x * 256 + threadIdx.x;
    if (t >= ksteps * nfrag * 64) return;
    int lane = t & 63, si = t >> 6;
    int i = si % nfrag, s = si / nfrag;
    int q = lane >> 4, n = (i << 4) + (lane & 15);
    unsigned short v[8];
#pragma unroll
    for (int j = 0; j < 8; j++) {
        int k = s * 32 + q * 8 + j;
        int sr = (batch_row >= 0 && k >= batch_row) ? k + 1 : k;
        v[j] = (sr < kmax_src && n < ncols) ? f2bf(W[(size_t)sr * ldw + n])
                                            : (unsigned short)0;
    }
    *(uint4*)&Wp[(size_t)t * 8] = *(const uint4*)v;
}

// ===========================================================================
// GEMM1: block = 64 edges x 256 cols, 4 waves; wave owns 64 cols (4 N-frags).
// K = 192; batch column applied rank-1 in epilogue.
// A staged through LDS (x already bf16 -> pure copy; ea converted), B dbuf.
// MODE 0: BN stats only (bucketed col sum/sumsq)            [fallback]
// MODE 1: CSR order, affine+ReLU, scatter-atomic into aggsum [fallback]
// MODE 2: NATURAL edge order (sequential edge_attr reads — proven optimal).
//         BN stats in regs + Y1 written at CSR position pos[e] via LDS
//         transpose as 512B full-row NONTEMPORAL bursts (410MB stream must
//         not thrash L2 — the x gather depends on L2/L3 residency).
// ===========================================================================
template <int MODE>
__global__ __launch_bounds__(256, 4) void gemm1_mfma(
    const unsigned short* __restrict__ xb, const int* __restrict__ rowi,
    const int* __restrict__ colE, const int* __restrict__ batch,
    const float* __restrict__ ea, const float* __restrict__ W1,
    const unsigned short* __restrict__ W1p, const int* __restrict__ eidx,
    const float* __restrict__ a1, const float* __restrict__ b1n,
    float* __restrict__ colsum_b, float* __restrict__ colsq_b,
    float* __restrict__ aggsum, unsigned short* __restrict__ y1c)
{
    __shared__ unsigned short Asm[64 * ALD];   // 26.6 KB; reused as transpose buf
    __shared__ int   rowS[64];
    __shared__ int   eSs[64];
    __shared__ float bvalS[64];
    __shared__ int   destS[64];

    const int tid = threadIdx.x;
    const int lane = tid & 63, wave = tid >> 6;
    const int quad = lane >> 4, l15 = lane & 15;
    const int e0 = blockIdx.x * 64;

    if (tid < 64) {
        int e = (MODE == 1) ? eidx[e0 + tid] : (e0 + tid);
        eSs[tid] = e;
        int r = rowi[e];
        rowS[tid] = r;
        bvalS[tid] = (float)batch[r];
        if (MODE == 1) destS[tid] = colE[e];
        if (MODE == 2) destS[tid] = eidx[e0 + tid];   // pos[e], e = e0+tid
    }
    __syncthreads();

    // ---- stage A into LDS: x part = 2048 uint2 (bf16 direct copy, cols
    // 0..127), ea = 1024 float4 + convert (cols 128..191). Consecutive lanes
    // -> consecutive addresses of the same row: full row bursts.
#pragma unroll
    for (int i = 0; i < 12; i++) {
        int idx = i * 256 + tid;
        if (idx < 2048) {                       // compile-time resolvable per i
            int row = idx >> 5, col4 = idx & 31;
            uint2 v = *(const uint2*)&xb[(size_t)rowS[row] * NF + col4 * 4];
            *(uint2*)&Asm[row * ALD + col4 * 4] = v;
        } else {
            int j = idx - 2048;
            int row = j >> 4, col4 = 32 + (j & 15);
            float4 v = *(const float4*)(ea + (size_t)eSs[row] * EF + (col4 - 32) * 4);
            ushort4 h;
            h.x = f2bf(v.x); h.y = f2bf(v.y); h.z = f2bf(v.z); h.w = f2bf(v.w);
            *(uint2*)&Asm[row * ALD + col4 * 4] = *(uint2*)&h;
        }
    }
    __syncthreads();

    const s16x8* Bp = (const s16x8*)W1p;
    f32x4 acc[4][4];
#pragma unroll
    for (int mf = 0; mf < 4; mf++)
#pragma unroll
        for (int f = 0; f < 4; f++) acc[mf][f] = (f32x4){0.f, 0.f, 0.f, 0.f};

    s16x8 bcur[4], bnxt[4];
#pragma unroll
    for (int f = 0; f < 4; f++)
        bcur[f] = Bp[(size_t)(wave * 4 + f) * 64 + lane];

#pragma unroll
    for (int s = 0; s < 6; s++) {
        if (s < 5) {
#pragma unroll
            for (int f = 0; f < 4; f++)
                bnxt[f] = Bp[(size_t)((s + 1) * 16 + wave * 4 + f) * 64 + lane];
        }
        s16x8 af[4];
#pragma unroll
        for (int mf = 0; mf < 4; mf++)
            af[mf] = *(const s16x8*)&Asm[(mf * 16 + l15) * ALD + s * 32 + quad * 8];
#pragma unroll
        for (int mf = 0; mf < 4; mf++)
#pragma unroll
            for (int f = 0; f < 4; f++)
                acc[mf][f] = __builtin_amdgcn_mfma_f32_16x16x32_bf16(
                    af[mf], bcur[f], acc[mf][f], 0, 0, 0);
#pragma unroll
        for (int f = 0; f < 4; f++) bcur[f] = bnxt[f];
    }

    // C/D: element r of lane = C[row = mf*16 + quad*4 + r][col = 16*i + l15]
    float bv[4][4];
#pragma unroll
    for (int mf = 0; mf < 4; mf++)
#pragma unroll
        for (int r = 0; r < 4; r++) bv[mf][r] = bvalS[mf * 16 + quad * 4 + r];

    if (MODE == 0) {
        const int bucket = blockIdx.x & 63;
#pragma unroll
        for (int f = 0; f < 4; f++) {
            const int col = ((wave * 4 + f) << 4) + l15;
            const float w1b = W1[(size_t)128 * LSZ + col];   // rank-1 batch row
            float s = 0.f, q = 0.f;
#pragma unroll
            for (int mf = 0; mf < 4; mf++)
#pragma unroll
                for (int r = 0; r < 4; r++) {
                    float y = fmaf(bv[mf][r], w1b, acc[mf][f][r]);
                    s += y; q += y * y;
                }
            s += __shfl_xor(s, 16); s += __shfl_xor(s, 32);
            q += __shfl_xor(q, 16); q += __shfl_xor(q, 32);
            if (quad == 0) {
                atomicAdd(&colsum_b[bucket * LSZ + col], s);
                atomicAdd(&colsq_b [bucket * LSZ + col], q);
            }
        }
    } else if (MODE == 2) {
        // ---- LDS-transpose epilogue: stats in regs, Y1 rows out as 512B bursts
        unsigned short* Tr = Asm;          // 32 rows x TLD bf16 = 16.9 KB
        float w1bf[4], sAcc[4] = {0.f,0.f,0.f,0.f}, qAcc[4] = {0.f,0.f,0.f,0.f};
#pragma unroll
        for (int f = 0; f < 4; f++)
            w1bf[f] = W1[(size_t)128 * LSZ + ((wave * 4 + f) << 4) + l15];

        __syncthreads();                   // all MFMA reads of Asm done
#pragma unroll
        for (int pass = 0; pass < 2; pass++) {
            if (pass) __syncthreads();     // pass0 reads done before overwrite
#pragma unroll
            for (int mfl = 0; mfl < 2; mfl++) {
                const int mf = pass * 2 + mfl;
#pragma unroll
                for (int f = 0; f < 4; f++) {
                    const int col = ((wave * 4 + f) << 4) + l15;
#pragma unroll
                    for (int r = 0; r < 4; r++) {
                        float y = fmaf(bv[mf][r], w1bf[f], acc[mf][f][r]);
                        sAcc[f] += y; qAcc[f] += y * y;
                        Tr[(mfl * 16 + quad * 4 + r) * TLD + col] = f2bf(y);
                    }
                }
            }
            __syncthreads();
            // 32 rows x 512B out; wave-instr = 2 rows x 512B contiguous (nt)
#pragma unroll
            for (int it = 0; it < 4; it++) {
                int chunk = it * 256 + tid;        // 0..1023
                int rl = chunk >> 5, c16 = chunk & 31;
                int grow = destS[pass * 32 + rl];
                u32x4 v = *(const u32x4*)&Tr[rl * TLD + c16 * 8];
                __builtin_nontemporal_store(v, (u32x4*)&y1c[(size_t)grow * LSZ + c16 * 8]);
            }
        }
        const int bucket = blockIdx.x & 63;
#pragma unroll
        for (int f = 0; f < 4; f++) {
            const int col = ((wave * 4 + f) << 4) + l15;
            float s = sAcc[f], q = qAcc[f];
            s += __shfl_xor(s, 16); s += __shfl_xor(s, 32);
            q += __shfl_xor(q, 16); q += __shfl_xor(q, 32);
            if (quad == 0) {
                atomicAdd(&colsum_b[bucket * LSZ + col], s);
                atomicAdd(&colsq_b [bucket * LSZ + col], q);
            }
        }
    } else {
        int dd[4][4];
#pragma unroll
        for (int mf = 0; mf < 4; mf++)
#pragma unroll
            for (int r = 0; r < 4; r++) dd[mf][r] = destS[mf * 16 + quad * 4 + r];
#pragma unroll
        for (int f = 0; f < 4; f++) {
            const int col = ((wave * 4 + f) << 4) + l15;
            const float w1b = W1[(size_t)128 * LSZ + col];
            const float Ac = a1[col], Bc = b1n[col];
#pragma unroll
            for (int mf = 0; mf < 4; mf++) {
                int cur = dd[mf][0];
                float run = fmaxf(fmaf(fmaf(bv[mf][0], w1b, acc[mf][f][0]), Ac, Bc), 0.f);
#pragma unroll
                for (int r = 1; r < 4; r++) {
                    float y = fmaxf(fmaf(fmaf(bv[mf][r], w1b, acc[mf][f][r]), Ac, Bc), 0.f);
                    if (dd[mf][r] != cur) {
                        atomicAdd(&aggsum[(size_t)cur * LSZ + col], run);
                        cur = dd[mf][r]; run = y;
                    } else run += y;
                }
                atomicAdd(&aggsum[(size_t)cur * LSZ + col], run);
            }
        }
    }
}

// ===========================================================================
// aggregate: aggb[n,c] = bf16( mean over CSR slots p of relu(a1*Y1c+b1n) )
// One WAVE per node; lane owns 4 cols (u32x2 = 8B) -> each slot read is one
// fully-coalesced 512B wave load (nontemporal: single-use stream).
// agg stored bf16 (identical numerics: gemm2 converts to bf16 anyway).
// ===========================================================================
__global__ __launch_bounds__(256, 8) void aggregate_kernel(
    const unsigned short* __restrict__ Y1c, const int* __restrict__ start,
    const float* __restrict__ a1, const float* __restrict__ b1n,
    unsigned short* __restrict__ aggb)
{
    const int gw = blockIdx.x * 4 + (threadIdx.x >> 6);   // node id
    if (gw >= NN) return;
    const int lane = threadIdx.x & 63;
    const int c0 = lane << 2;                             // 4 cols per lane
    const float4 av = *(const float4*)&a1[c0];
    const float4 bv = *(const float4*)&b1n[c0];
    const int p = start[gw], p1 = start[gw + 1];
    float a0 = 0.f, a1r = 0.f, a2r = 0.f, a3r = 0.f;
    const int sm = p1 - 1;
    for (int q = p; q < p1; q += 4) {
        u32x2 v[4];
#pragma unroll
        for (int j = 0; j < 4; j++) {
            int s = min(q + j, sm);
            v[j] = __builtin_nontemporal_load((const u32x2*)&Y1c[(size_t)s * LSZ + c0]);
        }
#pragma unroll
        for (int j = 0; j < 4; j++) {
            if (q + j < p1) {
                unsigned lo = v[j].x, hi = v[j].y;
                a0  += fmaxf(fmaf(bf2f((unsigned short)(lo & 0xffff)), av.x, bv.x), 0.f);
                a1r += fmaxf(fmaf(bf2f((unsigned short)(lo >> 16)),    av.y, bv.y), 0.f);
                a2r += fmaxf(fmaf(bf2f((unsigned short)(hi & 0xffff)), av.z, bv.z), 0.f);
                a3r += fmaxf(fmaf(bf2f((unsigned short)(hi >> 16)),    av.w, bv.w), 0.f);
            }
        }
    }
    const float inv = 1.0f / fmaxf((float)(p1 - p), 1.0f);
    unsigned short h[4] = {f2bf(a0 * inv), f2bf(a1r * inv),
                           f2bf(a2r * inv), f2bf(a3r * inv)};
    *(uint2*)&aggb[(size_t)gw * LSZ + c0] = *(const uint2*)h;
}

// ---------------------------------------------------------------------------
// finalize layer-1 BN: reduce 64 buckets, fold gamma/beta into affine a,b
// ---------------------------------------------------------------------------
__global__ void finalize1_kernel(
    const float* __restrict__ colsum_b, const float* __restrict__ colsq_b,
    const float* __restrict__ gamma, const float* __restrict__ beta,
    float* __restrict__ a, float* __restrict__ b)
{
    int c = threadIdx.x;  // 256
    float s = 0.f, q = 0.f;
    for (int bk = 0; bk < 64; bk++) {
        s += colsum_b[bk * LSZ + c];
        q += colsq_b [bk * LSZ + c];
    }
    float mu  = s * (1.0f / NE);
    float var = fmaxf(q * (1.0f / NE) - mu * mu, 0.f);
    float sc  = gamma[c] * rsqrtf(var + BN_EPS);
    a[c] = sc;
    b[c] = beta[c] - mu * sc;
}

// ---------------------------------------------------------------------------
// finalize layer-2 BN: reduce 64 buckets (stride Y2S), affine a2,b2n
// ---------------------------------------------------------------------------
__global__ void finalize2_kernel(
    const float* __restrict__ colsum_b, const float* __restrict__ colsq_b,
    const float* __restrict__ gamma, const float* __restrict__ beta,
    float* __restrict__ a, float* __restrict__ b)
{
    int c = blockIdx.x * 256 + threadIdx.x;
    if (c >= D2) return;
    float s = 0.f, q = 0.f;
    for (int bk = 0; bk < 64; bk++) {
        s += colsum_b[bk * Y2S + c];
        q += colsq_b [bk * Y2S + c];
    }
    float mu  = s * (1.0f / NN);
    float var = fmaxf(q * (1.0f / NN) - mu * mu, 0.f);
    float sc  = gamma[c] * rsqrtf(var + BN_EPS);
    a[c] = sc;
    b[c] = beta[c] - mu * sc;
}

// ---------------------------------------------------------------------------
// CSR build: histogram, single-block scan, slot fill (also emits pos[e])
// ---------------------------------------------------------------------------
__global__ void hist_kernel(const int* __restrict__ colE, int* __restrict__ cnt)
{
    int e = blockIdx.x * 256 + threadIdx.x;
    if (e < NE) atomicAdd(&cnt[colE[e]], 1);
}

__global__ __launch_bounds__(1024) void scan_kernel(
    const int* __restrict__ cnt, int* __restrict__ start, int n)
{
    __shared__ int wsum[16];
    __shared__ int carry_s;
    int tid = threadIdx.x;
    if (tid == 0) { carry_s = 0; start[0] = 0; }
    __syncthreads();
    for (int base = 0; base < n; base += 1024) {
        int i = base + tid;
        int v = (i < n) ? cnt[i] : 0;
        int lane = tid & 63, wave = tid >> 6;
        int sv = v;
#pragma unroll
        for (int off = 1; off < 64; off <<= 1) {
            int t = __shfl_up(sv, off);
            if (lane >= off) sv += t;
        }
        __syncthreads();
        if (lane == 63) wsum[wave] = sv;
        __syncthreads();
        int carry = carry_s;
        int woff = carry;
        for (int w = 0; w < wave; w++) woff += wsum[w];
        int incl = sv + woff;
        if (i < n) start[i + 1] = incl;
        int total = carry;
#pragma unroll
        for (int w = 0; w < 16; w++) total += wsum[w];
        __syncthreads();
        if (tid == 0) carry_s = total;
    }
}

__global__ void fill_kernel(const int* __restrict__ colE, const int* __restrict__ start,
                            int* __restrict__ cursor, int* __restrict__ eidx,
                            int* __restrict__ pos)
{
    int e = blockIdx.x * 256 + threadIdx.x;
    if (e < NE) {
        int c = colE[e];
        int p = start[c] + atomicAdd(&cursor[c], 1);
        eidx[p] = e;
        pos[e] = p;
    }
}

// ---------------------------------------------------------------------------
// fallback only: agg[n,c] = aggsum[n,c]/max(cnt,1), then bf16 into aggb
// ---------------------------------------------------------------------------
__global__ __launch_bounds__(256) void divcnt_kernel(
    const float* __restrict__ aggf, const int* __restrict__ cnt,
    unsigned short* __restrict__ aggb)
{
    int f = blockIdx.x * 256 + threadIdx.x;
    int n = f >> 6;                       // 64 float4 per 256-col row
    if (n < NN) {
        float inv = 1.0f / fmaxf((float)cnt[n], 1.0f);
        float4 v = ((const float4*)aggf)[f];
        unsigned short h[4] = {f2bf(v.x * inv), f2bf(v.y * inv),
                               f2bf(v.z * inv), f2bf(v.w * inv)};
        *(uint2*)&aggb[(size_t)f * 4] = *(const uint2*)h;
    }
}

// ===========================================================================
// GEMM2 (MFMA): Y2[n,c] = h2[n,:]·W2[:,c], batch rank-1 in epilogue,
// BN stats fused. K = 384 (xb 128 | aggb 256) — A loads are DIRECT bf16
// s16x8 (zero conversion; bit-identical since MFMA input was bf16 anyway).
// N padded to 416 (26 frags); grid.y in {0,1}. Y2 stored bf16, stride 416.
// ===========================================================================
__global__ __launch_bounds__(256, 3) void gemm2_mfma(
    const unsigned short* __restrict__ xb, const int* __restrict__ batch,
    const unsigned short* __restrict__ aggb, const float* __restrict__ W2,
    const unsigned short* __restrict__ W2p, unsigned short* __restrict__ Y2,
    float* __restrict__ colsum2_b, float* __restrict__ colsq2_b)
{
    __shared__ float bvalS[64];
    const int tid = threadIdx.x;
    const int lane = tid & 63, wave = tid >> 6;
    const int quad = lane >> 4, l15 = lane & 15;
    const int n0 = blockIdx.x * 64;
    const int fbase = blockIdx.y * 16 + wave * 4;

    if (tid < 64) bvalS[tid] = (float)batch[min(n0 + tid, NN - 1)];
    __syncthreads();

    int rn[4];
#pragma unroll
    for (int mf = 0; mf < 4; mf++) rn[mf] = min(n0 + mf * 16 + l15, NN - 1);

    const s16x8* Bp = (const s16x8*)W2p;
    f32x4 acc[4][4];
#pragma unroll
    for (int mf = 0; mf < 4; mf++)
#pragma unroll
        for (int f = 0; f < 4; f++) acc[mf][f] = (f32x4){0.f, 0.f, 0.f, 0.f};

    s16x8 bcur[4], bnxt[4];
#pragma unroll
    for (int f = 0; f < 4; f++)
        if (fbase + f < 26) bcur[f] = Bp[(size_t)(fbase + f) * 64 + lane];

#pragma unroll
    for (int s = 0; s < 12; s++) {
        if (s < 11) {
#pragma unroll
            for (int f = 0; f < 4; f++)
                if (fbase + f < 26)
                    bnxt[f] = Bp[(size_t)((s + 1) * 26 + fbase + f) * 64 + lane];
        }
        s16x8 af[4];
#pragma unroll
        for (int mf = 0; mf < 4; mf++) {
            af[mf] = (s < 4)
                ? *(const s16x8*)&xb  [(size_t)rn[mf] * NF  + s * 32 + quad * 8]
                : *(const s16x8*)&aggb[(size_t)rn[mf] * LSZ + (s - 4) * 32 + quad * 8];
        }
#pragma unroll
        for (int mf = 0; mf < 4; mf++)
#pragma unroll
            for (int f = 0; f < 4; f++)
                if (fbase + f < 26)
                    acc[mf][f] = __builtin_amdgcn_mfma_f32_16x16x32_bf16(
                        af[mf], bcur[f], acc[mf][f], 0, 0, 0);
#pragma unroll
        for (int f = 0; f < 4; f++) bcur[f] = bnxt[f];
    }

    float bv[4][4];
#pragma unroll
    for (int mf = 0; mf < 4; mf++)
#pragma unroll
        for (int r = 0; r < 4; r++) bv[mf][r] = bvalS[mf * 16 + quad * 4 + r];

    const int bucket = blockIdx.x & 63;
#pragma unroll
    for (int f = 0; f < 4; f++) {
        int i = fbase + f;
        if (i < 26) {
            const int col = (i << 4) + l15;
            const float w2b = (col < D2) ? W2[(size_t)128 * D2 + col] : 0.f;
            float s = 0.f, q = 0.f;
#pragma unroll
            for (int mf = 0; mf < 4; mf++)
#pragma unroll
                for (int r = 0; r < 4; r++) {
                    int n = n0 + mf * 16 + quad * 4 + r;
                    if (n < NN) {
                        float y = fmaf(bv[mf][r], w2b, acc[mf][f][r]);
                        Y2[(size_t)n * Y2S + col] = f2bf(y);
                        s += y; q += y * y;
                    }
                }
            s += __shfl_xor(s, 16); s += __shfl_xor(s, 32);
            q += __shfl_xor(q, 16); q += __shfl_xor(q, 32);
            if (quad == 0) {
                atomicAdd(&colsum2_b[bucket * Y2S + col], s);
                atomicAdd(&colsq2_b [bucket * Y2S + col], q);
            }
        }
    }
}

// ===========================================================================
// GEMM3 (MFMA): out[n,c] = relu( relu(a2⊙Y2[n,:]+b2n)·W3[:,c] + b3[c] )
// K = 416 (13 steps; pads have a2=b2n=0 -> A=0). N = 128 = 8 frags.
// ===========================================================================
__global__ __launch_bounds__(256, 3) void gemm3_mfma(
    const unsigned short* __restrict__ Y2, const float* __restrict__ a2,
    const float* __restrict__ b2n, const unsigned short* __restrict__ W3p,
    const float* __restrict__ b3, float* __restrict__ out)
{
    const int tid = threadIdx.x;
    const int lane = tid & 63, wave = tid >> 6;
    const int quad = lane >> 4, l15 = lane & 15;
    const int n0 = blockIdx.x * 64;

    int rn[4];
#pragma unroll
    for (int mf = 0; mf < 4; mf++) rn[mf] = min(n0 + mf * 16 + l15, NN - 1);

    const s16x8* Bp = (const s16x8*)W3p;
    f32x4 acc[4][2];
#pragma unroll
    for (int mf = 0; mf < 4; mf++)
#pragma unroll
        for (int f = 0; f < 2; f++) acc[mf][f] = (f32x4){0.f, 0.f, 0.f, 0.f};

    s16x8 bcur[2], bnxt[2];
#pragma unroll
    for (int f = 0; f < 2; f++)
        bcur[f] = Bp[(size_t)(wave * 2 + f) * 64 + lane];

#pragma unroll
    for (int s = 0; s < 13; s++) {
        if (s < 12) {
#pragma unroll
            for (int f = 0; f < 2; f++)
                bnxt[f] = Bp[(size_t)((s + 1) * 8 + wave * 2 + f) * 64 + lane];
        }
        const int kb = s * 32 + quad * 8;
        float4 A0 = *(const float4*)&a2[kb],  A1 = *(const float4*)&a2[kb + 4];
        float4 B0 = *(const float4*)&b2n[kb], B1 = *(const float4*)&b2n[kb + 4];
        float Aj[8] = {A0.x, A0.y, A0.z, A0.w, A1.x, A1.y, A1.z, A1.w};
        float Bj[8] = {B0.x, B0.y, B0.z, B0.w, B1.x, B1.y, B1.z, B1.w};
#pragma unroll
        for (int mf = 0; mf < 4; mf++) {
            s16x8 yv = *(const s16x8*)&Y2[(size_t)rn[mf] * Y2S + kb];
            s16x8 af;
#pragma unroll
            for (int j = 0; j < 8; j++) {
                float y = bf2f((unsigned short)yv[j]);
                y = fmaxf(fmaf(y, Aj[j], Bj[j]), 0.f);
                af[j] = (short)f2bf(y);
            }
#pragma unroll
            for (int f = 0; f < 2; f++)
                acc[mf][f] = __builtin_amdgcn_mfma_f32_16x16x32_bf16(
                    af, bcur[f], acc[mf][f], 0, 0, 0);
        }
#pragma unroll
        for (int f = 0; f < 2; f++) bcur[f] = bnxt[f];
    }

#pragma unroll
    for (int f = 0; f < 2; f++) {
        const int col = ((wave * 2 + f) << 4) + l15;
        const float bb = b3[col];
#pragma unroll
        for (int mf = 0; mf < 4; mf++)
#pragma unroll
            for (int r = 0; r < 4; r++) {
                int n = n0 + mf * 16 + quad * 4 + r;
                if (n < NN)
                    out[(size_t)n * NF + col] = fmaxf(acc[mf][f][r] + bb, 0.f);
            }
    }
}

// ---------------------------------------------------------------------------
extern "C" void kernel_launch(void* const* d_in, const int* in_sizes, int n_in,
                              void* d_out, int out_size, void* d_ws, size_t ws_size,
                              hipStream_t stream)
{
    const float* x         = (const float*)d_in[0];
    const int*   edge_idx  = (const int*)d_in[1];
    const float* edge_attr = (const float*)d_in[2];
    // d_in[3] = u : unused by the reference
    const int*   batch     = (const int*)d_in[4];
    const float* W1        = (const float*)d_in[5];
    // d_in[6] = b1 : cancelled by BatchNorm
    const float* g1        = (const float*)d_in[7];
    const float* be1       = (const float*)d_in[8];
    const float* W2        = (const float*)d_in[9];
    // d_in[10] = b2 : cancelled by BatchNorm
    const float* g2        = (const float*)d_in[11];
    const float* be2       = (const float*)d_in[12];
    const float* W3        = (const float*)d_in[13];
    const float* b3        = (const float*)d_in[14];
    float* out = (float*)d_out;

    const int* rowE = edge_idx;        // edge_index[0]
    const int* colE = edge_idx + NE;   // edge_index[1]

    // ---- workspace layout ----
    // xb (12.8MB) and aggb (25.6MB) are the bf16 operand stores.
    // Y1 (CSR-dest-ordered bf16, NE x 256 = 409.6 MB) aliases Y2 and beyond;
    // Y1 dies before gemm2 writes Y2.  aggf (fallback f32, 51.2MB) sits after
    // Y2 and is only used when Y1 doesn't fit.
    char* ws = (char*)d_ws;
    size_t off = 0;
    auto alloc = [&](size_t bytes) -> void* {
        void* p = ws + off;
        off += (bytes + 255) & ~(size_t)255;
        return p;
    };
    int*            eidx = (int*)alloc((size_t)NE * 4);                   //  3.2 MB
    int*            pos  = (int*)alloc((size_t)NE * 4);                   //  3.2 MB
    int*            start= (int*)alloc((size_t)(NN + 1) * 4);
    float*          a1   = (float*)alloc(LSZ * 4);
    float*          b1n  = (float*)alloc(LSZ * 4);
    unsigned short* W1p  = (unsigned short*)alloc((size_t)6  * 16 * 64 * 8 * 2); //  96 KB
    unsigned short* W2p  = (unsigned short*)alloc((size_t)12 * 26 * 64 * 8 * 2); // 312 KB
    unsigned short* W3p  = (unsigned short*)alloc((size_t)13 * 8  * 64 * 8 * 2); // 104 KB
    unsigned short* xb   = (unsigned short*)alloc((size_t)NN * NF * 2);   // 12.8 MB
    unsigned short* aggb = (unsigned short*)alloc((size_t)NN * LSZ * 2);  // 25.6 MB
    size_t zoff = off;                                             // ---- zero region ----
    int*   cnt       = (int*)  alloc((size_t)NN * 4);
    int*   cursor    = (int*)  alloc((size_t)NN * 4);
    float* colsum_b  = (float*)alloc(64 * LSZ * 4);
    float* colsq_b   = (float*)alloc(64 * LSZ * 4);
    float* colsum2_b = (float*)alloc(64 * Y2S * 4);                // 106 KB
    float* colsq2_b  = (float*)alloc(64 * Y2S * 4);
    float* a2        = (float*)alloc(Y2S * 4);   // pads (>=385) must stay 0
    float* b2n       = (float*)alloc(Y2S * 4);
    size_t zend = off;                                             // ---- end zero ----
    size_t y2off = off;
    unsigned short* Y2 = (unsigned short*)alloc((size_t)NN * Y2S * 2);    // 41.6 MB
    float* aggf      = (float*)alloc((size_t)NN * LSZ * 4);        // 51.2 MB (fallback)
    size_t total_base = off;
    size_t total_y1   = y2off + (size_t)NE * LSZ * 2;              // Y1 over Y2 + tail
    if (ws_size < total_base) return;
    const bool use_y1 = (ws_size >= total_y1);
    unsigned short* Y1 = (unsigned short*)(ws + y2off);

    hipMemsetAsync(ws + zoff, 0, zend - zoff, stream);
    if (!use_y1)
        hipMemsetAsync(aggf, 0, (size_t)NN * LSZ * 4, stream);

    // bf16 operand pre-packs
    cvt_x_kernel<<<(NN * NF / 8 + 255) / 256, 256, 0, stream>>>(x, xb);
    prep_w_kernel<<<(6  * 16 * 64 + 255) / 256, 256, 0, stream>>>(W1, LSZ, LSZ, D1, 128, 16, 6,  W1p);
    prep_w_kernel<<<(12 * 26 * 64 + 255) / 256, 256, 0, stream>>>(W2, D2,  D2,  D2, 128, 26, 12, W2p);
    prep_w_kernel<<<(13 * 8  * 64 + 255) / 256, 256, 0, stream>>>(W3, NF,  NF,  D2, -1,  8,  13, W3p);

    // CSR by destination node (+ inverse permutation pos[])
    hist_kernel<<<NE / 256, 256, 0, stream>>>(colE, cnt);
    scan_kernel<<<1, 1024, 0, stream>>>(cnt, start, NN);
    fill_kernel<<<NE / 256, 256, 0, stream>>>(colE, start, cursor, eidx, pos);

    if (use_y1) {
        // single edge-MLP pass (natural order): GEMM + BN stats + Y1 at CSR slot
        gemm1_mfma<2><<<NE / 64, 256, 0, stream>>>(
            xb, rowE, nullptr, batch, edge_attr, W1, W1p,
            pos, nullptr, nullptr, colsum_b, colsq_b, nullptr, Y1);
        finalize1_kernel<<<1, 256, 0, stream>>>(colsum_b, colsq_b, g1, be1, a1, b1n);
        // atomic-free streaming reduce over CSR ranges (mean + bf16 folded in)
        aggregate_kernel<<<(NN + 3) / 4, 256, 0, stream>>>(Y1, start, a1, b1n, aggb);
    } else {
        // fallback: original two-pass recompute + scatter-atomic path
        gemm1_mfma<0><<<NE / 64, 256, 0, stream>>>(
            xb, rowE, colE, batch, edge_attr, W1, W1p,
            nullptr, nullptr, nullptr, colsum_b, colsq_b, nullptr, nullptr);
        finalize1_kernel<<<1, 256, 0, stream>>>(colsum_b, colsq_b, g1, be1, a1, b1n);
        gemm1_mfma<1><<<NE / 64, 256, 0, stream>>>(
            xb, rowE, colE, batch, edge_attr, W1, W1p,
            eidx, a1, b1n, nullptr, nullptr, aggf, nullptr);
        divcnt_kernel<<<(NN * LSZ / 4) / 256, 256, 0, stream>>>(aggf, cnt, aggb);
    }

    // node MLP (MFMA, direct bf16 A loads, bf16 Y2, fused BN stats)
    gemm2_mfma<<<dim3((NN + 63) / 64, 2), 256, 0, stream>>>(
        xb, batch, aggb, W2, W2p, Y2, colsum2_b, colsq2_b);
    finalize2_kernel<<<2, 256, 0, stream>>>(colsum2_b, colsq2_b, g2, be2, a2, b2n);

    // output linear (MFMA, BN affine + ReLU fused into A build)
    gemm3_mfma<<<(NN + 63) / 64, 256, 0, stream>>>(Y2, a2, b2n, W3p, b3, out);
}